// Round 19
// baseline (1506.673 us; speedup 1.0000x reference)
//
#include <hip/hip_runtime.h>
#include <hip/hip_bf16.h>
#include <cstdint>

// Problem constants
constexpr int NB_ = 32;     // batch
constexpr int NS_ = 512;    // text length S
constexpr int NT_ = 2048;   // mel length T
constexpr int DMEL = 80;    // embedding dim

// ---------------- workspace layout ----------------
constexpr size_t P = 134217728ull;  // persistent block base
constexpr size_t PO_TE   = 0ull;
constexpr size_t PO_ME   = 5242880ull;
constexpr size_t PO_NA   = 26214400ull;
constexpr size_t PO_NB   = 26279936ull;
constexpr size_t PO_W1   = 27066368ull;
constexpr size_t PO_W2   = 28639232ull;
constexpr size_t PO_W3   = 28803072ull;
constexpr size_t PO_W4   = 28956672ull;
constexpr size_t PO_W5   = 29110272ull;
constexpr size_t PO_DIR  = 29139968ull;
constexpr size_t FULL_NEED = P + 33334528ull;

// ---------------- weight transpose: w(CO,CI,KW) -> wT[(tap*CI+ci)*CO+co] ----
__global__ void k_wtrans(const float* __restrict__ w, float* __restrict__ wT,
                         int CO, int CI, int KW, int total) {
  int id = blockIdx.x * 256 + threadIdx.x;
  if (id >= total) return;
  int co = id % CO;
  int rest = id / CO;
  int ci = rest % CI;
  int tap = rest / CI;
  wT[id] = w[(co * CI + ci) * KW + tap];
}

// ---------------- conv1d K=1 as implicit GEMM, optional fused row-norm ------
template <int CIN, int COUT, int NTILE, int NR, int KC, int LOG2L, int ACT,
          bool MASK, bool NORM>
__global__ __launch_bounds__(256) void k_conv(const float* __restrict__ x,
                                              const float* __restrict__ wT,
                                              const float* __restrict__ bias,
                                              float* __restrict__ y,
                                              const int* __restrict__ lenArr,
                                              float* __restrict__ normout) {
  constexpr int L = 1 << LOG2L;
  constexpr int MT = 128;
  constexpr int APAD = 132;
  constexpr int BPAD = NTILE + 4;
  __shared__ float As[KC][APAD];
  __shared__ float Bs[KC][BPAD];

  const int tid = threadIdx.x;
  const int tx = tid & 15;
  const int ty = tid >> 4;
  constexpr int NBLK = COUT / NTILE;
  const int m0 = (blockIdx.x / NBLK) * MT;
  const int n0 = (blockIdx.x % NBLK) * NTILE;

  float acc[8][NR];
#pragma unroll
  for (int i = 0; i < 8; ++i)
#pragma unroll
    for (int j = 0; j < NR; ++j) acc[i][j] = 0.f;

  for (int k0 = 0; k0 < CIN; k0 += KC) {
    __syncthreads();
    constexpr int AF4 = MT * KC / 4;
    constexpr int F4R = KC / 4;
    for (int f = tid; f < AF4; f += 256) {
      int row = f / F4R;
      int ko = (f % F4R) * 4;
      int r = m0 + row;
      float4 v = *reinterpret_cast<const float4*>(&x[(size_t)r * CIN + k0 + ko]);
      As[ko + 0][row] = v.x;
      As[ko + 1][row] = v.y;
      As[ko + 2][row] = v.z;
      As[ko + 3][row] = v.w;
    }
    constexpr int BF4 = KC * NTILE / 4;
    constexpr int BF4R = NTILE / 4;
    for (int f = tid; f < BF4; f += 256) {
      int kk = f / BF4R;
      int no = (f % BF4R) * 4;
      float4 v = *reinterpret_cast<const float4*>(
          &wT[((size_t)(k0 + kk)) * COUT + n0 + no]);
      *reinterpret_cast<float4*>(&Bs[kk][no]) = v;
    }
    __syncthreads();
#pragma unroll 8
    for (int kk = 0; kk < KC; ++kk) {
      float4 a0 = *reinterpret_cast<const float4*>(&As[kk][ty * 8]);
      float4 a1 = *reinterpret_cast<const float4*>(&As[kk][ty * 8 + 4]);
      float av[8] = {a0.x, a0.y, a0.z, a0.w, a1.x, a1.y, a1.z, a1.w};
      float bv[NR];
#pragma unroll
      for (int j = 0; j < NR; ++j) bv[j] = Bs[kk][tx * NR + j];
#pragma unroll
      for (int i = 0; i < 8; ++i)
#pragma unroll
        for (int j = 0; j < NR; ++j) acc[i][j] = fmaf(av[i], bv[j], acc[i][j]);
    }
  }
#pragma unroll
  for (int i = 0; i < 8; ++i) {
    int r = m0 + ty * 8 + i;
    int b = r >> LOG2L;
    int pos = r & (L - 1);
    bool zero = MASK && (pos >= lenArr[b]);
    float sq = 0.f;
#pragma unroll
    for (int j = 0; j < NR; ++j) {
      int c = n0 + tx * NR + j;
      float v = acc[i][j] + bias[c];
      if (ACT == 1) v = fmaxf(v, 0.f);
      if (ACT == 2) v = (v >= 0.f) ? v : 0.01f * v;
      if (zero) v = 0.f;
      y[(size_t)r * COUT + c] = v;
      if (NORM) sq = fmaf(v, v, sq);
    }
    if (NORM) {
      sq += __shfl_xor(sq, 1);
      sq += __shfl_xor(sq, 2);
      sq += __shfl_xor(sq, 4);
      sq += __shfl_xor(sq, 8);
      if (tx == 0) normout[r] = sq;
    }
  }
}

// ---------------- conv1d K=3: halo-staged A (once per k0), all taps inner ----
template <int CIN, int COUT, int NTILE, int NR, int KC, int LOG2L, int ACT>
__global__ __launch_bounds__(256) void k_conv3(const float* __restrict__ x,
                                               const float* __restrict__ wT,
                                               const float* __restrict__ bias,
                                               float* __restrict__ y) {
  constexpr int L = 1 << LOG2L;
  constexpr int MT = 128;
  constexpr int MT2 = MT + 2;
  constexpr int APAD = 132;
  constexpr int BPAD = NTILE + 4;
  __shared__ float As[KC][APAD];
  __shared__ float Bs[3][KC][BPAD];

  const int tid = threadIdx.x;
  const int tx = tid & 15;
  const int ty = tid >> 4;
  constexpr int NBLK = COUT / NTILE;
  const int m0 = (blockIdx.x / NBLK) * MT;
  const int n0 = (blockIdx.x % NBLK) * NTILE;
  const bool zlo = (m0 & (L - 1)) == 0;
  const bool zhi = ((m0 + MT) & (L - 1)) == 0;
  constexpr int TOTR = NB_ << LOG2L;

  float acc[8][NR];
#pragma unroll
  for (int i = 0; i < 8; ++i)
#pragma unroll
    for (int j = 0; j < NR; ++j) acc[i][j] = 0.f;

  for (int k0 = 0; k0 < CIN; k0 += KC) {
    __syncthreads();
    constexpr int F4R = KC / 4;
    for (int f = tid; f < MT2 * F4R; f += 256) {
      int h = f / F4R;
      int ko = (f % F4R) * 4;
      int g = m0 + h - 1;
      bool zero = (h == 0 && zlo) || (h == MT + 1 && zhi);
      int gc = g < 0 ? 0 : (g >= TOTR ? TOTR - 1 : g);
      float4 v = *reinterpret_cast<const float4*>(&x[(size_t)gc * CIN + k0 + ko]);
      if (zero) v = make_float4(0.f, 0.f, 0.f, 0.f);
      As[ko + 0][h] = v.x;
      As[ko + 1][h] = v.y;
      As[ko + 2][h] = v.z;
      As[ko + 3][h] = v.w;
    }
    constexpr int BF4R = NTILE / 4;
    for (int f = tid; f < 3 * KC * BF4R; f += 256) {
      int tap = f / (KC * BF4R);
      int rem = f % (KC * BF4R);
      int kk = rem / BF4R;
      int no = (rem % BF4R) * 4;
      float4 v = *reinterpret_cast<const float4*>(
          &wT[((size_t)(tap * CIN + k0 + kk)) * COUT + n0 + no]);
      *reinterpret_cast<float4*>(&Bs[tap][kk][no]) = v;
    }
    __syncthreads();
#pragma unroll 4
    for (int kk = 0; kk < KC; ++kk) {
      float aw[10];
      float4 a0 = *reinterpret_cast<const float4*>(&As[kk][ty * 8]);
      float4 a1 = *reinterpret_cast<const float4*>(&As[kk][ty * 8 + 4]);
      float2 a2 = *reinterpret_cast<const float2*>(&As[kk][ty * 8 + 8]);
      aw[0] = a0.x; aw[1] = a0.y; aw[2] = a0.z; aw[3] = a0.w;
      aw[4] = a1.x; aw[5] = a1.y; aw[6] = a1.z; aw[7] = a1.w;
      aw[8] = a2.x; aw[9] = a2.y;
#pragma unroll
      for (int tap = 0; tap < 3; ++tap) {
        float bv[NR];
#pragma unroll
        for (int j = 0; j < NR; ++j) bv[j] = Bs[tap][kk][tx * NR + j];
#pragma unroll
        for (int i = 0; i < 8; ++i)
#pragma unroll
          for (int j = 0; j < NR; ++j)
            acc[i][j] = fmaf(aw[i + tap], bv[j], acc[i][j]);
      }
    }
  }
#pragma unroll
  for (int i = 0; i < 8; ++i) {
    int r = m0 + ty * 8 + i;
#pragma unroll
    for (int j = 0; j < NR; ++j) {
      int c = n0 + tx * NR + j;
      float v = acc[i][j] + bias[c];
      if (ACT == 1) v = fmaxf(v, 0.f);
      if (ACT == 2) v = (v >= 0.f) ? v : 0.01f * v;
      y[(size_t)r * COUT + c] = v;
    }
  }
}

// ---------------- stats + logits + fused finalize (soft/rev/p) --------------
// Fully-masked t-tiles (t0 >= ml): skip GEMM/val entirely -> soft=0, rev=1.
__global__ __launch_bounds__(256) void k_stats3(
    const float* __restrict__ te, const float* __restrict__ me,
    const float* __restrict__ na, const float* __restrict__ nb,
    const int* __restrict__ src_len, const int* __restrict__ mel_len,
    float* __restrict__ val, float* __restrict__ soft, float* __restrict__ rev) {
  const int b = blockIdx.x >> 5;
  const int t0 = (blockIdx.x & 31) << 6;
  const int sl = src_len[b], ml = mel_len[b];
  const int tid = threadIdx.x;
  const int lane = tid & 63, w = tid >> 6;

  if (t0 >= ml) {  // block-uniform: whole t-tile masked
    for (int c = 0; c < 8; ++c) {
      const int s0 = c << 6;
#pragma unroll 4
      for (int i = 0; i < 16; ++i) {
        const int s = s0 + (w << 4) + i;
        size_t o = ((size_t)b * NS_ + s) * NT_ + t0 + lane;
        soft[o] = 0.f;
        rev[o] = 1.f;
      }
    }
    return;
  }

  __shared__ float Bt[DMEL][68];
  __shared__ float At[DMEL][68];
  __shared__ float redm[16][64];
  __shared__ float redz[16][64];
  __shared__ float sm[64];
  __shared__ float srz[64];
  __shared__ float pl[64][65];
  for (int f = tid; f < 64 * 20; f += 256) {
    int row = f / 20, ko = (f % 20) << 2;
    float4 v = *reinterpret_cast<const float4*>(
        &me[((size_t)b * NT_ + t0 + row) * DMEL + ko]);
    Bt[ko][row] = v.x; Bt[ko + 1][row] = v.y; Bt[ko + 2][row] = v.z; Bt[ko + 3][row] = v.w;
  }
  const int sy = tid & 15, tx = tid >> 4;
  const float NEGINF = -__builtin_inff();
  float nbv[4], mACC[4], zACC[4];
#pragma unroll
  for (int j = 0; j < 4; ++j) {
    nbv[j] = nb[b * NT_ + t0 + (tx << 2) + j];
    mACC[j] = NEGINF;
    zACC[j] = 0.f;
  }
  for (int c = 0; c < 8; ++c) {
    const int s0 = c << 6;
    __syncthreads();
    for (int f = tid; f < 64 * 20; f += 256) {
      int row = f / 20, ko = (f % 20) << 2;
      float4 v = *reinterpret_cast<const float4*>(
          &te[((size_t)b * NS_ + s0 + row) * DMEL + ko]);
      At[ko][row] = v.x; At[ko + 1][row] = v.y; At[ko + 2][row] = v.z; At[ko + 3][row] = v.w;
    }
    __syncthreads();
    float acc[4][4];
#pragma unroll
    for (int i = 0; i < 4; ++i)
#pragma unroll
      for (int j = 0; j < 4; ++j) acc[i][j] = 0.f;
#pragma unroll 8
    for (int kk = 0; kk < DMEL; ++kk) {
      float4 a = *reinterpret_cast<const float4*>(&At[kk][sy << 2]);
      float4 bb = *reinterpret_cast<const float4*>(&Bt[kk][tx << 2]);
      float av[4] = {a.x, a.y, a.z, a.w}, bv[4] = {bb.x, bb.y, bb.z, bb.w};
#pragma unroll
      for (int i = 0; i < 4; ++i)
#pragma unroll
        for (int j = 0; j < 4; ++j) acc[i][j] = fmaf(av[i], bv[j], acc[i][j]);
    }
    float nav[4];
#pragma unroll
    for (int i = 0; i < 4; ++i) nav[i] = na[b * NS_ + s0 + (sy << 2) + i];
#pragma unroll
    for (int j = 0; j < 4; ++j) {
      const int t = t0 + (tx << 2) + j;
      const bool tvalid = t < ml;
      float ov[4];
      float mNew = mACC[j];
#pragma unroll
      for (int i = 0; i < 4; ++i) {
        float d2 = (nav[i] + nbv[j]) - 2.0f * acc[i][j];
        float dist = sqrtf(fmaxf(d2, 1e-12f));
        bool valid = ((s0 + (sy << 2) + i) < sl) && tvalid;
        ov[i] = valid ? -dist : -1e9f;
        mNew = fmaxf(mNew, ov[i]);
      }
      float scale = expf(mACC[j] - mNew);
      float zadd = 0.f;
#pragma unroll
      for (int i = 0; i < 4; ++i) zadd += expf(ov[i] - mNew);
      zACC[j] = zACC[j] * scale + zadd;
      mACC[j] = mNew;
      float4 o = make_float4(ov[0], ov[1], ov[2], ov[3]);
      *reinterpret_cast<float4*>(&val[((size_t)b * NT_ + t) * NS_ + s0 + (sy << 2)]) = o;
    }
  }
#pragma unroll
  for (int j = 0; j < 4; ++j) {
    redm[sy][(tx << 2) + j] = mACC[j];
    redz[sy][(tx << 2) + j] = zACC[j];
  }
  __syncthreads();
  if (tid < 64) {
    float M = NEGINF, Z = 0.f;
#pragma unroll
    for (int y = 0; y < 16; ++y) {
      float m = redm[y][tid], z = redz[y][tid];
      float Mn = fmaxf(M, m);
      Z = Z * expf(M - Mn) + z * expf(m - Mn);
      M = Mn;
    }
    sm[tid] = M;
    srz[tid] = 1.0f / Z;
  }
  __syncthreads();

  // pass 2: normalize + transposed soft/rev writes
  for (int c = 0; c < 8; ++c) {
    const int s0 = c << 6;
#pragma unroll
    for (int j = 0; j < 4; ++j) {
      const int tl = (tx << 2) + j;
      const int t = t0 + tl;
      const bool tvalid = t < ml;
      const float mv = sm[tl];
      const float rzv = srz[tl];
      float* vp = &val[((size_t)b * NT_ + t) * NS_ + s0 + (sy << 2)];
      float4 ov = *reinterpret_cast<const float4*>(vp);
      float4 p;
      p.x = tvalid ? expf(ov.x - mv) * rzv : 0.f;
      p.y = tvalid ? expf(ov.y - mv) * rzv : 0.f;
      p.z = tvalid ? expf(ov.z - mv) * rzv : 0.f;
      p.w = tvalid ? expf(ov.w - mv) * rzv : 0.f;
      *reinterpret_cast<float4*>(vp) = p;
      pl[tl][(sy << 2) + 0] = p.x;
      pl[tl][(sy << 2) + 1] = p.y;
      pl[tl][(sy << 2) + 2] = p.z;
      pl[tl][(sy << 2) + 3] = p.w;
    }
    __syncthreads();
#pragma unroll 4
    for (int i = 0; i < 16; ++i) {
      const int s_loc = (w << 4) + i;
      const int s = s0 + s_loc;
      float p = pl[lane][s_loc];
      size_t o = ((size_t)b * NS_ + s) * NT_ + t0 + lane;
      soft[o] = p;
      bool r = (s >= sl) || ((t0 + lane) >= ml);
      rev[o] = r ? 1.0f : 0.0f;
    }
    __syncthreads();
  }
}

// lane i <- lane i-1 via DPP wave_shr:1 (VALU, no LDS pipe). Lane 0 -> 0.
__device__ __forceinline__ float dp_shr1(float x) {
  int r = __builtin_amdgcn_update_dpp(0, __float_as_int(x), 0x138, 0xF, 0xF, true);
  return __int_as_float(r);
}

// RAW barrier: lgkmcnt(0) for cross-wave ds_write visibility, no vmcnt drain.
__device__ __forceinline__ void dp_bar() {
  asm volatile("s_waitcnt lgkmcnt(0)" ::: "memory");
  __builtin_amdgcn_sched_barrier(0);
  __builtin_amdgcn_s_barrier();
}

// Consumer chunk body: 16 rows, 4-row register batches. MASKED = apply (s<=t).
#define DP_CHUNK(MASKED)                                                      \
  _Pragma("unroll")                                                           \
  for (int rb8 = 0; rb8 < 4; ++rb8) {                                         \
    float4 d0[4], d1[4];                                                      \
    _Pragma("unroll")                                                         \
    for (int rr = 0; rr < 4; ++rr) {                                          \
      const float* rp = rowbase + (((rb8 << 2) + rr) << 9);                   \
      d0[rr] = *reinterpret_cast<const float4*>(rp + (lane << 2));            \
      d1[rr] = *reinterpret_cast<const float4*>(rp + 256 + (lane << 2));      \
    }                                                                         \
    _Pragma("unroll")                                                         \
    for (int rr = 0; rr < 4; ++rr) {                                          \
      const int t = tbase + (rb8 << 2) + rr;                                  \
      float cc[8] = {d0[rr].x, d0[rr].y, d0[rr].z, d0[rr].w,                  \
                     d1[rr].x, d1[rr].y, d1[rr].z, d1[rr].w};                 \
      const int sh = t & 31;                                                  \
      if (t < ml) {                                                           \
        float up = dp_shr1(v[7]);                                             \
        float prev = (lane == 0) ? NEGINF : up;                               \
        _Pragma("unroll")                                                     \
        for (int j = 0; j < 8; ++j) {                                         \
          float cur = v[j];                                                   \
          bool keep = cur >= prev;                                            \
          float vm = fmaxf(cur, prev);                                        \
          float vn;                                                           \
          if (MASKED) {                                                       \
            int s = (lane << 3) + j;                                          \
            vn = (s <= t) ? vm + cc[j] : NEGINF;                              \
          } else {                                                            \
            vn = vm + cc[j];                                                  \
          }                                                                   \
          uint32_t bit = keep ? 1u : inv[j];                                  \
          bw[j] |= bit << sh;                                                 \
          v[j] = vn;                                                          \
          prev = cur;                                                         \
        }                                                                     \
      } else {                                                                \
        _Pragma("unroll")                                                     \
        for (int j = 0; j < 8; ++j) bw[j] |= 1u << sh;                        \
      }                                                                       \
    }                                                                         \
  }

// ---------------- DP forward scan: 1 consumer + 2 reg-staging producer waves ----
__global__ __launch_bounds__(192) void k_dp(const float* __restrict__ val,
                                            const int* __restrict__ src_len,
                                            const int* __restrict__ mel_len,
                                            uint32_t* __restrict__ dir) {
  __shared__ float buf[2][16][512];  // 64 KB double buffer
  const int b = blockIdx.x;
  const int wv = threadIdx.x >> 6;   // 0 = consumer, 1..2 = producers
  const int lane = threadIdx.x & 63;
  const float* base = val + (size_t)b * NT_ * NS_;
  const int sl = src_len[b];
  const int ml = mel_len[b];
  const float NEGINF = -__builtin_inff();
  int ca = ((ml + 31) >> 5) << 1;
  const int C_act = ca > 128 ? 128 : ca;

  float4 ra[8], rb[8];
  const int r0 = (wv - 1) << 3;

  float v[8];
  uint32_t bw[8], inv[8];
#pragma unroll
  for (int j = 0; j < 8; ++j) {
    v[j] = 0.0f;
    bw[j] = 0u;
    int s = (lane << 3) + j;
    inv[j] = (s < sl) ? 0u : 1u;
  }

  if (wv > 0) {
#pragma unroll
    for (int rr = 0; rr < 8; ++rr) {
      const float* g = base + (size_t)(r0 + rr) * NS_;
      ra[rr] = *reinterpret_cast<const float4*>(g + (lane << 3));
      rb[rr] = *reinterpret_cast<const float4*>(g + (lane << 3) + 4);
    }
#pragma unroll
    for (int rr = 0; rr < 8; ++rr) {
      float* l = &buf[0][r0 + rr][0];
      *reinterpret_cast<float4*>(l + (lane << 2)) = ra[rr];
      *reinterpret_cast<float4*>(l + 256 + (lane << 2)) = rb[rr];
    }
#pragma unroll
    for (int rr = 0; rr < 8; ++rr) {
      const float* g = base + (size_t)(16 + r0 + rr) * NS_;
      ra[rr] = *reinterpret_cast<const float4*>(g + (lane << 3));
      rb[rr] = *reinterpret_cast<const float4*>(g + (lane << 3) + 4);
    }
  }
  dp_bar();

  for (int c = 0; c < C_act; ++c) {
    if (wv > 0) {
      if (c + 1 < C_act) {
        const int nb = (c + 1) & 1;
#pragma unroll
        for (int rr = 0; rr < 8; ++rr) {
          float* l = &buf[nb][r0 + rr][0];
          *reinterpret_cast<float4*>(l + (lane << 2)) = ra[rr];
          *reinterpret_cast<float4*>(l + 256 + (lane << 2)) = rb[rr];
        }
      }
      if (c + 2 < C_act) {
        const float* cb = base + ((size_t)(c + 2) * 16 + r0) * NS_;
#pragma unroll
        for (int rr = 0; rr < 8; ++rr) {
          const float* g = cb + (size_t)rr * NS_;
          ra[rr] = *reinterpret_cast<const float4*>(g + (lane << 3));
          rb[rr] = *reinterpret_cast<const float4*>(g + (lane << 3) + 4);
        }
      }
    } else {
      const float* rowbase = &buf[c & 1][0][0];
      const int tbase = c << 4;
      if (c < 32) {
        DP_CHUNK(true)
      } else {
        DP_CHUNK(false)
      }
      if (c & 1) {
        const int c32 = c >> 1;
#pragma unroll
        for (int j = 0; j < 8; ++j) {
          dir[((size_t)(b * NS_) + (lane << 3) + j) * 64 + c32] = bw[j];
          bw[j] = 0u;
        }
      }
    }
    dp_bar();
  }
  if (wv == 0) {
    for (int c32 = C_act >> 1; c32 < 64; ++c32) {
#pragma unroll
      for (int j = 0; j < 8; ++j)
        dir[((size_t)(b * NS_) + (lane << 3) + j) * 64 + c32] = 0xFFFFFFFFu;
    }
  }
}

// ---------------- backtrack + full hard-tile write (absorbs memset) ---------
// Phase 1: load dir bits to LDS; tid0 walks the path into plds[t].
// Phase 2: all 256 threads write the entire (S,T) tile:
//          hard[s][t] = (plds[t]==s && t<ml) ? 1 : 0   (coalesced in t).
__global__ __launch_bounds__(256) void k_backtrack(
    const uint32_t* __restrict__ dir, const int* __restrict__ src_len,
    const int* __restrict__ mel_len, float* __restrict__ hard) {
  __shared__ uint32_t dl[NS_ * 64];  // 128 KB
  __shared__ int plds[NT_];          // 8 KB
  const int b = blockIdx.x, tid = threadIdx.x;
  const uint32_t* db = dir + (size_t)b * NS_ * 64;
  for (int f = tid; f < 8192; f += 256) {
    int s = f >> 4;
    int wo = (f & 15) << 2;
    *reinterpret_cast<uint4*>(&dl[s * 64 + wo]) =
        *reinterpret_cast<const uint4*>(&db[s * 64 + wo]);
  }
  __syncthreads();
  if (tid == 0) {
    int idx = src_len[b] - 1;
    if (idx < 0) idx = 0;
    if (idx > NS_ - 1) idx = NS_ - 1;
    int cw = -1, ci = -1;
    uint32_t w = 0;
    for (int t = NT_ - 1; t >= 0; --t) {
      int wi = t >> 5;
      if (wi != cw || idx != ci) {
        w = dl[idx * 64 + wi];
        cw = wi;
        ci = idx;
      }
      plds[t] = idx;
      int step = (int)((w >> (t & 31)) & 1) - 1;
      idx += step;
      if (idx < 0) idx = 0;
    }
  }
  __syncthreads();
  // phase 2: each thread owns 8 consecutive t (2 float4 stores per row)
  const int ml = mel_len[b];
  const int tq = tid << 3;  // this thread's t base
  int pv[8];
  float msk[8];
#pragma unroll
  for (int k = 0; k < 8; ++k) {
    pv[k] = plds[tq + k];
    msk[k] = (tq + k < ml) ? 1.0f : 0.0f;
  }
  float* hb = hard + (size_t)b * NS_ * NT_;
  for (int s = 0; s < NS_; ++s) {
    float o[8];
#pragma unroll
    for (int k = 0; k < 8; ++k) o[k] = (pv[k] == s) ? msk[k] : 0.0f;
    float4* dst = reinterpret_cast<float4*>(hb + (size_t)s * NT_ + tq);
    dst[0] = make_float4(o[0], o[1], o[2], o[3]);
    dst[1] = make_float4(o[4], o[5], o[6], o[7]);
  }
}

// ---------------- host launch ----------------
extern "C" void kernel_launch(void* const* d_in, const int* in_sizes, int n_in,
                              void* d_out, int out_size, void* d_ws, size_t ws_size,
                              hipStream_t stream) {
  if (n_in != 17) return;
  if (ws_size < FULL_NEED) return;

  const float* text = (const float*)d_in[0];
  const float* mel = (const float*)d_in[1];
  const int* src_len = (const int*)d_in[2];
  const int* mel_len = (const int*)d_in[3];
  const float* tw1 = (const float*)d_in[7];
  const float* tb1 = (const float*)d_in[8];
  const float* tw2 = (const float*)d_in[9];
  const float* tb2 = (const float*)d_in[10];
  const float* mw1 = (const float*)d_in[11];
  const float* mb1 = (const float*)d_in[12];
  const float* mw2 = (const float*)d_in[13];
  const float* mb2 = (const float*)d_in[14];
  const float* mw3 = (const float*)d_in[15];
  const float* mb3 = (const float*)d_in[16];

  char* w8 = (char*)d_ws;
  float* melh1 = (float*)(w8 + 0);            // (B,T,160) 41.9 MB
  float* mh2 = (float*)(w8 + 41943040ull);    // (B,T,80)  21.0 MB
  float* texth1 = (float*)(w8 + 62914560ull); // (B,S,512) 33.5 MB
  float* val = (float*)(w8 + 0);              // (B,T,S) written after convs

  float* te = (float*)(w8 + P + PO_TE);
  float* me = (float*)(w8 + P + PO_ME);
  float* na = (float*)(w8 + P + PO_NA);
  float* nb = (float*)(w8 + P + PO_NB);
  float* wt1 = (float*)(w8 + P + PO_W1);
  float* wt2 = (float*)(w8 + P + PO_W2);
  float* wt3 = (float*)(w8 + P + PO_W3);
  float* wt4 = (float*)(w8 + P + PO_W4);
  float* wt5 = (float*)(w8 + P + PO_W5);
  uint32_t* dir = (uint32_t*)(w8 + P + PO_DIR);

  // outputs are float32
  float* soft = (float*)d_out;
  float* hard = soft + (size_t)NB_ * NS_ * NT_;
  float* rev = soft + 2 * (size_t)NB_ * NS_ * NT_;

  // weight transposes (f32 direct)
  k_wtrans<<<(512 * 256 * 3 + 255) / 256, 256, 0, stream>>>(tw1, wt1, 512, 256, 3, 512 * 256 * 3);
  k_wtrans<<<(80 * 512 + 255) / 256, 256, 0, stream>>>(tw2, wt2, 80, 512, 1, 80 * 512);
  k_wtrans<<<(160 * 80 * 3 + 255) / 256, 256, 0, stream>>>(mw1, wt3, 160, 80, 3, 160 * 80 * 3);
  k_wtrans<<<(80 * 160 * 3 + 255) / 256, 256, 0, stream>>>(mw2, wt4, 80, 160, 3, 80 * 160 * 3);
  k_wtrans<<<(80 * 80 + 255) / 256, 256, 0, stream>>>(mw3, wt5, 80, 80, 1, 80 * 80);

  // encoders (inputs read directly as f32); norms fused into final convs
  k_conv3<80, 160, 80, 5, 16, 11, 2><<<512 * 2, 256, 0, stream>>>(mel, wt3, mb1, melh1);
  k_conv3<160, 80, 80, 5, 32, 11, 2><<<512 * 1, 256, 0, stream>>>(melh1, wt4, mb2, mh2);
  k_conv<80, 80, 80, 5, 16, 11, 0, true, true><<<512 * 1, 256, 0, stream>>>(mh2, wt5, mb3, me, mel_len, nb);
  k_conv3<256, 512, 128, 8, 32, 9, 1><<<128 * 4, 256, 0, stream>>>(text, wt1, tb1, texth1);
  k_conv<512, 80, 80, 5, 32, 9, 0, true, true><<<128 * 1, 256, 0, stream>>>(texth1, wt2, tb2, te, src_len, na);

  // stats + logits + fused finalize (val=p, soft, rev)
  k_stats3<<<NB_ * 32, 256, 0, stream>>>(te, me, na, nb, src_len, mel_len, val, soft, rev);

  // DP + backtrack (backtrack also writes the zero background of hard)
  k_dp<<<NB_, 192, 0, stream>>>(val, src_len, mel_len, dir);
  k_backtrack<<<NB_, 256, 0, stream>>>(dir, src_len, mel_len, hard);
}

// Round 20
// 1131.022 us; speedup vs baseline: 1.3321x; 1.3321x over previous
//
#include <hip/hip_runtime.h>
#include <hip/hip_bf16.h>
#include <cstdint>

// Problem constants
constexpr int NB_ = 32;     // batch
constexpr int NS_ = 512;    // text length S
constexpr int NT_ = 2048;   // mel length T
constexpr int DMEL = 80;    // embedding dim

// ---------------- workspace layout ----------------
constexpr size_t P = 134217728ull;  // persistent block base
constexpr size_t PO_TE   = 0ull;
constexpr size_t PO_ME   = 5242880ull;
constexpr size_t PO_NA   = 26214400ull;
constexpr size_t PO_NB   = 26279936ull;
constexpr size_t PO_W1   = 27066368ull;
constexpr size_t PO_W2   = 28639232ull;
constexpr size_t PO_W3   = 28803072ull;
constexpr size_t PO_W4   = 28956672ull;
constexpr size_t PO_W5   = 29110272ull;
constexpr size_t PO_DIR  = 29139968ull;
constexpr size_t FULL_NEED = P + 33334528ull;

// ---------------- weight transpose: w(CO,CI,KW) -> wT[(tap*CI+ci)*CO+co] ----
__global__ void k_wtrans(const float* __restrict__ w, float* __restrict__ wT,
                         int CO, int CI, int KW, int total) {
  int id = blockIdx.x * 256 + threadIdx.x;
  if (id >= total) return;
  int co = id % CO;
  int rest = id / CO;
  int ci = rest % CI;
  int tap = rest / CI;
  wT[id] = w[(co * CI + ci) * KW + tap];
}

// ---------------- conv1d K=1 as implicit GEMM, optional fused row-norm ------
template <int CIN, int COUT, int NTILE, int NR, int KC, int LOG2L, int ACT,
          bool MASK, bool NORM>
__global__ __launch_bounds__(256) void k_conv(const float* __restrict__ x,
                                              const float* __restrict__ wT,
                                              const float* __restrict__ bias,
                                              float* __restrict__ y,
                                              const int* __restrict__ lenArr,
                                              float* __restrict__ normout) {
  constexpr int L = 1 << LOG2L;
  constexpr int MT = 128;
  constexpr int APAD = 132;
  constexpr int BPAD = NTILE + 4;
  __shared__ float As[KC][APAD];
  __shared__ float Bs[KC][BPAD];

  const int tid = threadIdx.x;
  const int tx = tid & 15;
  const int ty = tid >> 4;
  constexpr int NBLK = COUT / NTILE;
  const int m0 = (blockIdx.x / NBLK) * MT;
  const int n0 = (blockIdx.x % NBLK) * NTILE;

  float acc[8][NR];
#pragma unroll
  for (int i = 0; i < 8; ++i)
#pragma unroll
    for (int j = 0; j < NR; ++j) acc[i][j] = 0.f;

  for (int k0 = 0; k0 < CIN; k0 += KC) {
    __syncthreads();
    constexpr int AF4 = MT * KC / 4;
    constexpr int F4R = KC / 4;
    for (int f = tid; f < AF4; f += 256) {
      int row = f / F4R;
      int ko = (f % F4R) * 4;
      int r = m0 + row;
      float4 v = *reinterpret_cast<const float4*>(&x[(size_t)r * CIN + k0 + ko]);
      As[ko + 0][row] = v.x;
      As[ko + 1][row] = v.y;
      As[ko + 2][row] = v.z;
      As[ko + 3][row] = v.w;
    }
    constexpr int BF4 = KC * NTILE / 4;
    constexpr int BF4R = NTILE / 4;
    for (int f = tid; f < BF4; f += 256) {
      int kk = f / BF4R;
      int no = (f % BF4R) * 4;
      float4 v = *reinterpret_cast<const float4*>(
          &wT[((size_t)(k0 + kk)) * COUT + n0 + no]);
      *reinterpret_cast<float4*>(&Bs[kk][no]) = v;
    }
    __syncthreads();
#pragma unroll 8
    for (int kk = 0; kk < KC; ++kk) {
      float4 a0 = *reinterpret_cast<const float4*>(&As[kk][ty * 8]);
      float4 a1 = *reinterpret_cast<const float4*>(&As[kk][ty * 8 + 4]);
      float av[8] = {a0.x, a0.y, a0.z, a0.w, a1.x, a1.y, a1.z, a1.w};
      float bv[NR];
#pragma unroll
      for (int j = 0; j < NR; ++j) bv[j] = Bs[kk][tx * NR + j];
#pragma unroll
      for (int i = 0; i < 8; ++i)
#pragma unroll
        for (int j = 0; j < NR; ++j) acc[i][j] = fmaf(av[i], bv[j], acc[i][j]);
    }
  }
#pragma unroll
  for (int i = 0; i < 8; ++i) {
    int r = m0 + ty * 8 + i;
    int b = r >> LOG2L;
    int pos = r & (L - 1);
    bool zero = MASK && (pos >= lenArr[b]);
    float sq = 0.f;
#pragma unroll
    for (int j = 0; j < NR; ++j) {
      int c = n0 + tx * NR + j;
      float v = acc[i][j] + bias[c];
      if (ACT == 1) v = fmaxf(v, 0.f);
      if (ACT == 2) v = (v >= 0.f) ? v : 0.01f * v;
      if (zero) v = 0.f;
      y[(size_t)r * COUT + c] = v;
      if (NORM) sq = fmaf(v, v, sq);
    }
    if (NORM) {
      sq += __shfl_xor(sq, 1);
      sq += __shfl_xor(sq, 2);
      sq += __shfl_xor(sq, 4);
      sq += __shfl_xor(sq, 8);
      if (tx == 0) normout[r] = sq;
    }
  }
}

// ---------------- conv1d K=3: halo-staged A (once per k0), all taps inner ----
template <int CIN, int COUT, int NTILE, int NR, int KC, int LOG2L, int ACT>
__global__ __launch_bounds__(256) void k_conv3(const float* __restrict__ x,
                                               const float* __restrict__ wT,
                                               const float* __restrict__ bias,
                                               float* __restrict__ y) {
  constexpr int L = 1 << LOG2L;
  constexpr int MT = 128;
  constexpr int MT2 = MT + 2;
  constexpr int APAD = 132;
  constexpr int BPAD = NTILE + 4;
  __shared__ float As[KC][APAD];
  __shared__ float Bs[3][KC][BPAD];

  const int tid = threadIdx.x;
  const int tx = tid & 15;
  const int ty = tid >> 4;
  constexpr int NBLK = COUT / NTILE;
  const int m0 = (blockIdx.x / NBLK) * MT;
  const int n0 = (blockIdx.x % NBLK) * NTILE;
  const bool zlo = (m0 & (L - 1)) == 0;
  const bool zhi = ((m0 + MT) & (L - 1)) == 0;
  constexpr int TOTR = NB_ << LOG2L;

  float acc[8][NR];
#pragma unroll
  for (int i = 0; i < 8; ++i)
#pragma unroll
    for (int j = 0; j < NR; ++j) acc[i][j] = 0.f;

  for (int k0 = 0; k0 < CIN; k0 += KC) {
    __syncthreads();
    constexpr int F4R = KC / 4;
    for (int f = tid; f < MT2 * F4R; f += 256) {
      int h = f / F4R;
      int ko = (f % F4R) * 4;
      int g = m0 + h - 1;
      bool zero = (h == 0 && zlo) || (h == MT + 1 && zhi);
      int gc = g < 0 ? 0 : (g >= TOTR ? TOTR - 1 : g);
      float4 v = *reinterpret_cast<const float4*>(&x[(size_t)gc * CIN + k0 + ko]);
      if (zero) v = make_float4(0.f, 0.f, 0.f, 0.f);
      As[ko + 0][h] = v.x;
      As[ko + 1][h] = v.y;
      As[ko + 2][h] = v.z;
      As[ko + 3][h] = v.w;
    }
    constexpr int BF4R = NTILE / 4;
    for (int f = tid; f < 3 * KC * BF4R; f += 256) {
      int tap = f / (KC * BF4R);
      int rem = f % (KC * BF4R);
      int kk = rem / BF4R;
      int no = (rem % BF4R) * 4;
      float4 v = *reinterpret_cast<const float4*>(
          &wT[((size_t)(tap * CIN + k0 + kk)) * COUT + n0 + no]);
      *reinterpret_cast<float4*>(&Bs[tap][kk][no]) = v;
    }
    __syncthreads();
#pragma unroll 4
    for (int kk = 0; kk < KC; ++kk) {
      float aw[10];
      float4 a0 = *reinterpret_cast<const float4*>(&As[kk][ty * 8]);
      float4 a1 = *reinterpret_cast<const float4*>(&As[kk][ty * 8 + 4]);
      float2 a2 = *reinterpret_cast<const float2*>(&As[kk][ty * 8 + 8]);
      aw[0] = a0.x; aw[1] = a0.y; aw[2] = a0.z; aw[3] = a0.w;
      aw[4] = a1.x; aw[5] = a1.y; aw[6] = a1.z; aw[7] = a1.w;
      aw[8] = a2.x; aw[9] = a2.y;
#pragma unroll
      for (int tap = 0; tap < 3; ++tap) {
        float bv[NR];
#pragma unroll
        for (int j = 0; j < NR; ++j) bv[j] = Bs[tap][kk][tx * NR + j];
#pragma unroll
        for (int i = 0; i < 8; ++i)
#pragma unroll
          for (int j = 0; j < NR; ++j)
            acc[i][j] = fmaf(aw[i + tap], bv[j], acc[i][j]);
      }
    }
  }
#pragma unroll
  for (int i = 0; i < 8; ++i) {
    int r = m0 + ty * 8 + i;
#pragma unroll
    for (int j = 0; j < NR; ++j) {
      int c = n0 + tx * NR + j;
      float v = acc[i][j] + bias[c];
      if (ACT == 1) v = fmaxf(v, 0.f);
      if (ACT == 2) v = (v >= 0.f) ? v : 0.01f * v;
      y[(size_t)r * COUT + c] = v;
    }
  }
}

// ---------------- stats + logits + fused finalize (soft/rev/p) --------------
// Fully-masked t-tiles (t0 >= ml): skip GEMM/val entirely -> soft=0, rev=1.
__global__ __launch_bounds__(256) void k_stats3(
    const float* __restrict__ te, const float* __restrict__ me,
    const float* __restrict__ na, const float* __restrict__ nb,
    const int* __restrict__ src_len, const int* __restrict__ mel_len,
    float* __restrict__ val, float* __restrict__ soft, float* __restrict__ rev) {
  const int b = blockIdx.x >> 5;
  const int t0 = (blockIdx.x & 31) << 6;
  const int sl = src_len[b], ml = mel_len[b];
  const int tid = threadIdx.x;
  const int lane = tid & 63, w = tid >> 6;

  if (t0 >= ml) {  // block-uniform: whole t-tile masked
    for (int c = 0; c < 8; ++c) {
      const int s0 = c << 6;
#pragma unroll 4
      for (int i = 0; i < 16; ++i) {
        const int s = s0 + (w << 4) + i;
        size_t o = ((size_t)b * NS_ + s) * NT_ + t0 + lane;
        soft[o] = 0.f;
        rev[o] = 1.f;
      }
    }
    return;
  }

  __shared__ float Bt[DMEL][68];
  __shared__ float At[DMEL][68];
  __shared__ float redm[16][64];
  __shared__ float redz[16][64];
  __shared__ float sm[64];
  __shared__ float srz[64];
  __shared__ float pl[64][65];
  for (int f = tid; f < 64 * 20; f += 256) {
    int row = f / 20, ko = (f % 20) << 2;
    float4 v = *reinterpret_cast<const float4*>(
        &me[((size_t)b * NT_ + t0 + row) * DMEL + ko]);
    Bt[ko][row] = v.x; Bt[ko + 1][row] = v.y; Bt[ko + 2][row] = v.z; Bt[ko + 3][row] = v.w;
  }
  const int sy = tid & 15, tx = tid >> 4;
  const float NEGINF = -__builtin_inff();
  float nbv[4], mACC[4], zACC[4];
#pragma unroll
  for (int j = 0; j < 4; ++j) {
    nbv[j] = nb[b * NT_ + t0 + (tx << 2) + j];
    mACC[j] = NEGINF;
    zACC[j] = 0.f;
  }
  for (int c = 0; c < 8; ++c) {
    const int s0 = c << 6;
    __syncthreads();
    for (int f = tid; f < 64 * 20; f += 256) {
      int row = f / 20, ko = (f % 20) << 2;
      float4 v = *reinterpret_cast<const float4*>(
          &te[((size_t)b * NS_ + s0 + row) * DMEL + ko]);
      At[ko][row] = v.x; At[ko + 1][row] = v.y; At[ko + 2][row] = v.z; At[ko + 3][row] = v.w;
    }
    __syncthreads();
    float acc[4][4];
#pragma unroll
    for (int i = 0; i < 4; ++i)
#pragma unroll
      for (int j = 0; j < 4; ++j) acc[i][j] = 0.f;
#pragma unroll 8
    for (int kk = 0; kk < DMEL; ++kk) {
      float4 a = *reinterpret_cast<const float4*>(&At[kk][sy << 2]);
      float4 bb = *reinterpret_cast<const float4*>(&Bt[kk][tx << 2]);
      float av[4] = {a.x, a.y, a.z, a.w}, bv[4] = {bb.x, bb.y, bb.z, bb.w};
#pragma unroll
      for (int i = 0; i < 4; ++i)
#pragma unroll
        for (int j = 0; j < 4; ++j) acc[i][j] = fmaf(av[i], bv[j], acc[i][j]);
    }
    float nav[4];
#pragma unroll
    for (int i = 0; i < 4; ++i) nav[i] = na[b * NS_ + s0 + (sy << 2) + i];
#pragma unroll
    for (int j = 0; j < 4; ++j) {
      const int t = t0 + (tx << 2) + j;
      const bool tvalid = t < ml;
      float ov[4];
      float mNew = mACC[j];
#pragma unroll
      for (int i = 0; i < 4; ++i) {
        float d2 = (nav[i] + nbv[j]) - 2.0f * acc[i][j];
        float dist = sqrtf(fmaxf(d2, 1e-12f));
        bool valid = ((s0 + (sy << 2) + i) < sl) && tvalid;
        ov[i] = valid ? -dist : -1e9f;
        mNew = fmaxf(mNew, ov[i]);
      }
      float scale = expf(mACC[j] - mNew);
      float zadd = 0.f;
#pragma unroll
      for (int i = 0; i < 4; ++i) zadd += expf(ov[i] - mNew);
      zACC[j] = zACC[j] * scale + zadd;
      mACC[j] = mNew;
      float4 o = make_float4(ov[0], ov[1], ov[2], ov[3]);
      *reinterpret_cast<float4*>(&val[((size_t)b * NT_ + t) * NS_ + s0 + (sy << 2)]) = o;
    }
  }
#pragma unroll
  for (int j = 0; j < 4; ++j) {
    redm[sy][(tx << 2) + j] = mACC[j];
    redz[sy][(tx << 2) + j] = zACC[j];
  }
  __syncthreads();
  if (tid < 64) {
    float M = NEGINF, Z = 0.f;
#pragma unroll
    for (int y = 0; y < 16; ++y) {
      float m = redm[y][tid], z = redz[y][tid];
      float Mn = fmaxf(M, m);
      Z = Z * expf(M - Mn) + z * expf(m - Mn);
      M = Mn;
    }
    sm[tid] = M;
    srz[tid] = 1.0f / Z;
  }
  __syncthreads();

  // pass 2: normalize + transposed soft/rev writes
  for (int c = 0; c < 8; ++c) {
    const int s0 = c << 6;
#pragma unroll
    for (int j = 0; j < 4; ++j) {
      const int tl = (tx << 2) + j;
      const int t = t0 + tl;
      const bool tvalid = t < ml;
      const float mv = sm[tl];
      const float rzv = srz[tl];
      float* vp = &val[((size_t)b * NT_ + t) * NS_ + s0 + (sy << 2)];
      float4 ov = *reinterpret_cast<const float4*>(vp);
      float4 p;
      p.x = tvalid ? expf(ov.x - mv) * rzv : 0.f;
      p.y = tvalid ? expf(ov.y - mv) * rzv : 0.f;
      p.z = tvalid ? expf(ov.z - mv) * rzv : 0.f;
      p.w = tvalid ? expf(ov.w - mv) * rzv : 0.f;
      *reinterpret_cast<float4*>(vp) = p;
      pl[tl][(sy << 2) + 0] = p.x;
      pl[tl][(sy << 2) + 1] = p.y;
      pl[tl][(sy << 2) + 2] = p.z;
      pl[tl][(sy << 2) + 3] = p.w;
    }
    __syncthreads();
#pragma unroll 4
    for (int i = 0; i < 16; ++i) {
      const int s_loc = (w << 4) + i;
      const int s = s0 + s_loc;
      float p = pl[lane][s_loc];
      size_t o = ((size_t)b * NS_ + s) * NT_ + t0 + lane;
      soft[o] = p;
      bool r = (s >= sl) || ((t0 + lane) >= ml);
      rev[o] = r ? 1.0f : 0.0f;
    }
    __syncthreads();
  }
}

// lane i <- lane i-1 via DPP wave_shr:1 (VALU, no LDS pipe). Lane 0 -> 0.
__device__ __forceinline__ float dp_shr1(float x) {
  int r = __builtin_amdgcn_update_dpp(0, __float_as_int(x), 0x138, 0xF, 0xF, true);
  return __int_as_float(r);
}

// RAW barrier: lgkmcnt(0) for cross-wave ds_write visibility, no vmcnt drain.
__device__ __forceinline__ void dp_bar() {
  asm volatile("s_waitcnt lgkmcnt(0)" ::: "memory");
  __builtin_amdgcn_sched_barrier(0);
  __builtin_amdgcn_s_barrier();
}

// Consumer chunk body: 16 rows, 4-row register batches. MASKED = apply (s<=t).
#define DP_CHUNK(MASKED)                                                      \
  _Pragma("unroll")                                                           \
  for (int rb8 = 0; rb8 < 4; ++rb8) {                                         \
    float4 d0[4], d1[4];                                                      \
    _Pragma("unroll")                                                         \
    for (int rr = 0; rr < 4; ++rr) {                                          \
      const float* rp = rowbase + (((rb8 << 2) + rr) << 9);                   \
      d0[rr] = *reinterpret_cast<const float4*>(rp + (lane << 2));            \
      d1[rr] = *reinterpret_cast<const float4*>(rp + 256 + (lane << 2));      \
    }                                                                         \
    _Pragma("unroll")                                                         \
    for (int rr = 0; rr < 4; ++rr) {                                          \
      const int t = tbase + (rb8 << 2) + rr;                                  \
      float cc[8] = {d0[rr].x, d0[rr].y, d0[rr].z, d0[rr].w,                  \
                     d1[rr].x, d1[rr].y, d1[rr].z, d1[rr].w};                 \
      const int sh = t & 31;                                                  \
      if (t < ml) {                                                           \
        float up = dp_shr1(v[7]);                                             \
        float prev = (lane == 0) ? NEGINF : up;                               \
        _Pragma("unroll")                                                     \
        for (int j = 0; j < 8; ++j) {                                         \
          float cur = v[j];                                                   \
          bool keep = cur >= prev;                                            \
          float vm = fmaxf(cur, prev);                                        \
          float vn;                                                           \
          if (MASKED) {                                                       \
            int s = (lane << 3) + j;                                          \
            vn = (s <= t) ? vm + cc[j] : NEGINF;                              \
          } else {                                                            \
            vn = vm + cc[j];                                                  \
          }                                                                   \
          uint32_t bit = keep ? 1u : inv[j];                                  \
          bw[j] |= bit << sh;                                                 \
          v[j] = vn;                                                          \
          prev = cur;                                                         \
        }                                                                     \
      } else {                                                                \
        _Pragma("unroll")                                                     \
        for (int j = 0; j < 8; ++j) bw[j] |= 1u << sh;                        \
      }                                                                       \
    }                                                                         \
  }

// ---------------- DP forward scan: 1 consumer + 2 reg-staging producer waves ----
__global__ __launch_bounds__(192) void k_dp(const float* __restrict__ val,
                                            const int* __restrict__ src_len,
                                            const int* __restrict__ mel_len,
                                            uint32_t* __restrict__ dir) {
  __shared__ float buf[2][16][512];  // 64 KB double buffer
  const int b = blockIdx.x;
  const int wv = threadIdx.x >> 6;   // 0 = consumer, 1..2 = producers
  const int lane = threadIdx.x & 63;
  const float* base = val + (size_t)b * NT_ * NS_;
  const int sl = src_len[b];
  const int ml = mel_len[b];
  const float NEGINF = -__builtin_inff();
  int ca = ((ml + 31) >> 5) << 1;
  const int C_act = ca > 128 ? 128 : ca;

  float4 ra[8], rb[8];
  const int r0 = (wv - 1) << 3;

  float v[8];
  uint32_t bw[8], inv[8];
#pragma unroll
  for (int j = 0; j < 8; ++j) {
    v[j] = 0.0f;
    bw[j] = 0u;
    int s = (lane << 3) + j;
    inv[j] = (s < sl) ? 0u : 1u;
  }

  if (wv > 0) {
#pragma unroll
    for (int rr = 0; rr < 8; ++rr) {
      const float* g = base + (size_t)(r0 + rr) * NS_;
      ra[rr] = *reinterpret_cast<const float4*>(g + (lane << 3));
      rb[rr] = *reinterpret_cast<const float4*>(g + (lane << 3) + 4);
    }
#pragma unroll
    for (int rr = 0; rr < 8; ++rr) {
      float* l = &buf[0][r0 + rr][0];
      *reinterpret_cast<float4*>(l + (lane << 2)) = ra[rr];
      *reinterpret_cast<float4*>(l + 256 + (lane << 2)) = rb[rr];
    }
#pragma unroll
    for (int rr = 0; rr < 8; ++rr) {
      const float* g = base + (size_t)(16 + r0 + rr) * NS_;
      ra[rr] = *reinterpret_cast<const float4*>(g + (lane << 3));
      rb[rr] = *reinterpret_cast<const float4*>(g + (lane << 3) + 4);
    }
  }
  dp_bar();

  for (int c = 0; c < C_act; ++c) {
    if (wv > 0) {
      if (c + 1 < C_act) {
        const int nb = (c + 1) & 1;
#pragma unroll
        for (int rr = 0; rr < 8; ++rr) {
          float* l = &buf[nb][r0 + rr][0];
          *reinterpret_cast<float4*>(l + (lane << 2)) = ra[rr];
          *reinterpret_cast<float4*>(l + 256 + (lane << 2)) = rb[rr];
        }
      }
      if (c + 2 < C_act) {
        const float* cb = base + ((size_t)(c + 2) * 16 + r0) * NS_;
#pragma unroll
        for (int rr = 0; rr < 8; ++rr) {
          const float* g = cb + (size_t)rr * NS_;
          ra[rr] = *reinterpret_cast<const float4*>(g + (lane << 3));
          rb[rr] = *reinterpret_cast<const float4*>(g + (lane << 3) + 4);
        }
      }
    } else {
      const float* rowbase = &buf[c & 1][0][0];
      const int tbase = c << 4;
      if (c < 32) {
        DP_CHUNK(true)
      } else {
        DP_CHUNK(false)
      }
      if (c & 1) {
        const int c32 = c >> 1;
#pragma unroll
        for (int j = 0; j < 8; ++j) {
          dir[((size_t)(b * NS_) + (lane << 3) + j) * 64 + c32] = bw[j];
          bw[j] = 0u;
        }
      }
    }
    dp_bar();
  }
  if (wv == 0) {
    for (int c32 = C_act >> 1; c32 < 64; ++c32) {
#pragma unroll
      for (int j = 0; j < 8; ++j)
        dir[((size_t)(b * NS_) + (lane << 3) + j) * 64 + c32] = 0xFFFFFFFFu;
    }
  }
}

// ---------------- backtrack: single phase, full-T bit plane in 128 KB LDS ----
// Scatter-only writes (background zeroed by hipMemsetAsync at ~device BW).
__global__ __launch_bounds__(256) void k_backtrack(
    const uint32_t* __restrict__ dir, const int* __restrict__ src_len,
    const int* __restrict__ mel_len, float* __restrict__ hard) {
  __shared__ uint32_t dl[NS_ * 64];  // 128 KB
  const int b = blockIdx.x, tid = threadIdx.x;
  const uint32_t* db = dir + (size_t)b * NS_ * 64;
  for (int f = tid; f < 8192; f += 256) {
    int s = f >> 4;
    int wo = (f & 15) << 2;
    *reinterpret_cast<uint4*>(&dl[s * 64 + wo]) =
        *reinterpret_cast<const uint4*>(&db[s * 64 + wo]);
  }
  __syncthreads();
  if (tid == 0) {
    const int ml = mel_len[b];
    int idx = src_len[b] - 1;
    if (idx < 0) idx = 0;
    if (idx > NS_ - 1) idx = NS_ - 1;
    int cw = -1, ci = -1;
    uint32_t w = 0;
    for (int t = NT_ - 1; t >= 0; --t) {
      int wi = t >> 5;
      if (wi != cw || idx != ci) {
        w = dl[idx * 64 + wi];
        cw = wi;
        ci = idx;
      }
      if (t < ml) hard[((size_t)(b * NS_) + idx) * NT_ + t] = 1.0f;
      int step = (int)((w >> (t & 31)) & 1) - 1;
      idx += step;
      if (idx < 0) idx = 0;
    }
  }
}

// ---------------- host launch ----------------
extern "C" void kernel_launch(void* const* d_in, const int* in_sizes, int n_in,
                              void* d_out, int out_size, void* d_ws, size_t ws_size,
                              hipStream_t stream) {
  if (n_in != 17) return;
  if (ws_size < FULL_NEED) return;

  const float* text = (const float*)d_in[0];
  const float* mel = (const float*)d_in[1];
  const int* src_len = (const int*)d_in[2];
  const int* mel_len = (const int*)d_in[3];
  const float* tw1 = (const float*)d_in[7];
  const float* tb1 = (const float*)d_in[8];
  const float* tw2 = (const float*)d_in[9];
  const float* tb2 = (const float*)d_in[10];
  const float* mw1 = (const float*)d_in[11];
  const float* mb1 = (const float*)d_in[12];
  const float* mw2 = (const float*)d_in[13];
  const float* mb2 = (const float*)d_in[14];
  const float* mw3 = (const float*)d_in[15];
  const float* mb3 = (const float*)d_in[16];

  char* w8 = (char*)d_ws;
  float* melh1 = (float*)(w8 + 0);            // (B,T,160) 41.9 MB
  float* mh2 = (float*)(w8 + 41943040ull);    // (B,T,80)  21.0 MB
  float* texth1 = (float*)(w8 + 62914560ull); // (B,S,512) 33.5 MB
  float* val = (float*)(w8 + 0);              // (B,T,S) written after convs

  float* te = (float*)(w8 + P + PO_TE);
  float* me = (float*)(w8 + P + PO_ME);
  float* na = (float*)(w8 + P + PO_NA);
  float* nb = (float*)(w8 + P + PO_NB);
  float* wt1 = (float*)(w8 + P + PO_W1);
  float* wt2 = (float*)(w8 + P + PO_W2);
  float* wt3 = (float*)(w8 + P + PO_W3);
  float* wt4 = (float*)(w8 + P + PO_W4);
  float* wt5 = (float*)(w8 + P + PO_W5);
  uint32_t* dir = (uint32_t*)(w8 + P + PO_DIR);

  // outputs are float32
  float* soft = (float*)d_out;
  float* hard = soft + (size_t)NB_ * NS_ * NT_;
  float* rev = soft + 2 * (size_t)NB_ * NS_ * NT_;

  // weight transposes (f32 direct)
  k_wtrans<<<(512 * 256 * 3 + 255) / 256, 256, 0, stream>>>(tw1, wt1, 512, 256, 3, 512 * 256 * 3);
  k_wtrans<<<(80 * 512 + 255) / 256, 256, 0, stream>>>(tw2, wt2, 80, 512, 1, 80 * 512);
  k_wtrans<<<(160 * 80 * 3 + 255) / 256, 256, 0, stream>>>(mw1, wt3, 160, 80, 3, 160 * 80 * 3);
  k_wtrans<<<(80 * 160 * 3 + 255) / 256, 256, 0, stream>>>(mw2, wt4, 80, 160, 3, 80 * 160 * 3);
  k_wtrans<<<(80 * 80 + 255) / 256, 256, 0, stream>>>(mw3, wt5, 80, 80, 1, 80 * 80);

  // encoders (inputs read directly as f32); norms fused into final convs
  k_conv3<80, 160, 80, 5, 16, 11, 2><<<512 * 2, 256, 0, stream>>>(mel, wt3, mb1, melh1);
  k_conv3<160, 80, 80, 5, 32, 11, 2><<<512 * 1, 256, 0, stream>>>(melh1, wt4, mb2, mh2);
  k_conv<80, 80, 80, 5, 16, 11, 0, true, true><<<512 * 1, 256, 0, stream>>>(mh2, wt5, mb3, me, mel_len, nb);
  k_conv3<256, 512, 128, 8, 32, 9, 1><<<128 * 4, 256, 0, stream>>>(text, wt1, tb1, texth1);
  k_conv<512, 80, 80, 5, 32, 9, 0, true, true><<<128 * 1, 256, 0, stream>>>(texth1, wt2, tb2, te, src_len, na);

  // hard_A zero early (device-wide memset BW), scatter fills the path later
  hipMemsetAsync(hard, 0, (size_t)NB_ * NS_ * NT_ * 4, stream);

  // stats + logits + fused finalize (val=p, soft, rev)
  k_stats3<<<NB_ * 32, 256, 0, stream>>>(te, me, na, nb, src_len, mel_len, val, soft, rev);

  // DP + backtrack
  k_dp<<<NB_, 192, 0, stream>>>(val, src_len, mel_len, dir);
  k_backtrack<<<NB_, 256, 0, stream>>>(dir, src_len, mel_len, hard);
}

// Round 21
// 1114.217 us; speedup vs baseline: 1.3522x; 1.0151x over previous
//
#include <hip/hip_runtime.h>
#include <hip/hip_bf16.h>
#include <cstdint>

// Problem constants
constexpr int NB_ = 32;     // batch
constexpr int NS_ = 512;    // text length S
constexpr int NT_ = 2048;   // mel length T
constexpr int DMEL = 80;    // embedding dim

// ---------------- workspace layout ----------------
constexpr size_t P = 134217728ull;  // persistent block base
constexpr size_t PO_TE   = 0ull;
constexpr size_t PO_ME   = 5242880ull;
constexpr size_t PO_NA   = 26214400ull;
constexpr size_t PO_NB   = 26279936ull;
constexpr size_t PO_W1   = 27066368ull;
constexpr size_t PO_W2   = 28639232ull;
constexpr size_t PO_W3   = 28803072ull;
constexpr size_t PO_W4   = 28956672ull;
constexpr size_t PO_W5   = 29110272ull;
constexpr size_t PO_DIR  = 29139968ull;
constexpr size_t FULL_NEED = P + 33334528ull;

// ---------------- fused weight transposes (all 5 weights, one launch) -------
// w(CO,CI,KW) -> wT[(tap*CI+ci)*CO+co], segments laid out back to back.
__global__ void k_wtrans_all(const float* __restrict__ w1, float* __restrict__ o1,
                             const float* __restrict__ w2, float* __restrict__ o2,
                             const float* __restrict__ w3, float* __restrict__ o3,
                             const float* __restrict__ w4, float* __restrict__ o4,
                             const float* __restrict__ w5, float* __restrict__ o5) {
  int id = blockIdx.x * 256 + threadIdx.x;
  const float* w;
  float* o;
  int CO, CI, KW;
  // segment sizes: 393216, 40960, 38400, 38400, 6400
  if (id < 393216) {
    w = w1; o = o1; CO = 512; CI = 256; KW = 3;
  } else if (id < 434176) {
    id -= 393216; w = w2; o = o2; CO = 80; CI = 512; KW = 1;
  } else if (id < 472576) {
    id -= 434176; w = w3; o = o3; CO = 160; CI = 80; KW = 3;
  } else if (id < 510976) {
    id -= 472576; w = w4; o = o4; CO = 80; CI = 160; KW = 3;
  } else if (id < 517376) {
    id -= 510976; w = w5; o = o5; CO = 80; CI = 80; KW = 1;
  } else {
    return;
  }
  int co = id % CO;
  int rest = id / CO;
  int ci = rest % CI;
  int tap = rest / CI;
  o[id] = w[(co * CI + ci) * KW + tap];
}

// ---------------- conv1d K=1 as implicit GEMM, optional fused row-norm ------
template <int CIN, int COUT, int NTILE, int NR, int KC, int LOG2L, int ACT,
          bool MASK, bool NORM>
__global__ __launch_bounds__(256) void k_conv(const float* __restrict__ x,
                                              const float* __restrict__ wT,
                                              const float* __restrict__ bias,
                                              float* __restrict__ y,
                                              const int* __restrict__ lenArr,
                                              float* __restrict__ normout) {
  constexpr int L = 1 << LOG2L;
  constexpr int MT = 128;
  constexpr int APAD = 132;
  constexpr int BPAD = NTILE + 4;
  __shared__ float As[KC][APAD];
  __shared__ float Bs[KC][BPAD];

  const int tid = threadIdx.x;
  const int tx = tid & 15;
  const int ty = tid >> 4;
  constexpr int NBLK = COUT / NTILE;
  const int m0 = (blockIdx.x / NBLK) * MT;
  const int n0 = (blockIdx.x % NBLK) * NTILE;

  float acc[8][NR];
#pragma unroll
  for (int i = 0; i < 8; ++i)
#pragma unroll
    for (int j = 0; j < NR; ++j) acc[i][j] = 0.f;

  for (int k0 = 0; k0 < CIN; k0 += KC) {
    __syncthreads();
    constexpr int AF4 = MT * KC / 4;
    constexpr int F4R = KC / 4;
    for (int f = tid; f < AF4; f += 256) {
      int row = f / F4R;
      int ko = (f % F4R) * 4;
      int r = m0 + row;
      float4 v = *reinterpret_cast<const float4*>(&x[(size_t)r * CIN + k0 + ko]);
      As[ko + 0][row] = v.x;
      As[ko + 1][row] = v.y;
      As[ko + 2][row] = v.z;
      As[ko + 3][row] = v.w;
    }
    constexpr int BF4 = KC * NTILE / 4;
    constexpr int BF4R = NTILE / 4;
    for (int f = tid; f < BF4; f += 256) {
      int kk = f / BF4R;
      int no = (f % BF4R) * 4;
      float4 v = *reinterpret_cast<const float4*>(
          &wT[((size_t)(k0 + kk)) * COUT + n0 + no]);
      *reinterpret_cast<float4*>(&Bs[kk][no]) = v;
    }
    __syncthreads();
#pragma unroll 8
    for (int kk = 0; kk < KC; ++kk) {
      float4 a0 = *reinterpret_cast<const float4*>(&As[kk][ty * 8]);
      float4 a1 = *reinterpret_cast<const float4*>(&As[kk][ty * 8 + 4]);
      float av[8] = {a0.x, a0.y, a0.z, a0.w, a1.x, a1.y, a1.z, a1.w};
      float bv[NR];
#pragma unroll
      for (int j = 0; j < NR; ++j) bv[j] = Bs[kk][tx * NR + j];
#pragma unroll
      for (int i = 0; i < 8; ++i)
#pragma unroll
        for (int j = 0; j < NR; ++j) acc[i][j] = fmaf(av[i], bv[j], acc[i][j]);
    }
  }
#pragma unroll
  for (int i = 0; i < 8; ++i) {
    int r = m0 + ty * 8 + i;
    int b = r >> LOG2L;
    int pos = r & (L - 1);
    bool zero = MASK && (pos >= lenArr[b]);
    float sq = 0.f;
#pragma unroll
    for (int j = 0; j < NR; ++j) {
      int c = n0 + tx * NR + j;
      float v = acc[i][j] + bias[c];
      if (ACT == 1) v = fmaxf(v, 0.f);
      if (ACT == 2) v = (v >= 0.f) ? v : 0.01f * v;
      if (zero) v = 0.f;
      y[(size_t)r * COUT + c] = v;
      if (NORM) sq = fmaf(v, v, sq);
    }
    if (NORM) {
      sq += __shfl_xor(sq, 1);
      sq += __shfl_xor(sq, 2);
      sq += __shfl_xor(sq, 4);
      sq += __shfl_xor(sq, 8);
      if (tx == 0) normout[r] = sq;
    }
  }
}

// ---------------- conv1d K=3: halo-staged A (once per k0), all taps inner ----
template <int CIN, int COUT, int NTILE, int NR, int KC, int LOG2L, int ACT>
__global__ __launch_bounds__(256) void k_conv3(const float* __restrict__ x,
                                               const float* __restrict__ wT,
                                               const float* __restrict__ bias,
                                               float* __restrict__ y) {
  constexpr int L = 1 << LOG2L;
  constexpr int MT = 128;
  constexpr int MT2 = MT + 2;
  constexpr int APAD = 132;
  constexpr int BPAD = NTILE + 4;
  __shared__ float As[KC][APAD];
  __shared__ float Bs[3][KC][BPAD];

  const int tid = threadIdx.x;
  const int tx = tid & 15;
  const int ty = tid >> 4;
  constexpr int NBLK = COUT / NTILE;
  const int m0 = (blockIdx.x / NBLK) * MT;
  const int n0 = (blockIdx.x % NBLK) * NTILE;
  const bool zlo = (m0 & (L - 1)) == 0;
  const bool zhi = ((m0 + MT) & (L - 1)) == 0;
  constexpr int TOTR = NB_ << LOG2L;

  float acc[8][NR];
#pragma unroll
  for (int i = 0; i < 8; ++i)
#pragma unroll
    for (int j = 0; j < NR; ++j) acc[i][j] = 0.f;

  for (int k0 = 0; k0 < CIN; k0 += KC) {
    __syncthreads();
    constexpr int F4R = KC / 4;
    for (int f = tid; f < MT2 * F4R; f += 256) {
      int h = f / F4R;
      int ko = (f % F4R) * 4;
      int g = m0 + h - 1;
      bool zero = (h == 0 && zlo) || (h == MT + 1 && zhi);
      int gc = g < 0 ? 0 : (g >= TOTR ? TOTR - 1 : g);
      float4 v = *reinterpret_cast<const float4*>(&x[(size_t)gc * CIN + k0 + ko]);
      if (zero) v = make_float4(0.f, 0.f, 0.f, 0.f);
      As[ko + 0][h] = v.x;
      As[ko + 1][h] = v.y;
      As[ko + 2][h] = v.z;
      As[ko + 3][h] = v.w;
    }
    constexpr int BF4R = NTILE / 4;
    for (int f = tid; f < 3 * KC * BF4R; f += 256) {
      int tap = f / (KC * BF4R);
      int rem = f % (KC * BF4R);
      int kk = rem / BF4R;
      int no = (rem % BF4R) * 4;
      float4 v = *reinterpret_cast<const float4*>(
          &wT[((size_t)(tap * CIN + k0 + kk)) * COUT + n0 + no]);
      *reinterpret_cast<float4*>(&Bs[tap][kk][no]) = v;
    }
    __syncthreads();
#pragma unroll 4
    for (int kk = 0; kk < KC; ++kk) {
      float aw[10];
      float4 a0 = *reinterpret_cast<const float4*>(&As[kk][ty * 8]);
      float4 a1 = *reinterpret_cast<const float4*>(&As[kk][ty * 8 + 4]);
      float2 a2 = *reinterpret_cast<const float2*>(&As[kk][ty * 8 + 8]);
      aw[0] = a0.x; aw[1] = a0.y; aw[2] = a0.z; aw[3] = a0.w;
      aw[4] = a1.x; aw[5] = a1.y; aw[6] = a1.z; aw[7] = a1.w;
      aw[8] = a2.x; aw[9] = a2.y;
#pragma unroll
      for (int tap = 0; tap < 3; ++tap) {
        float bv[NR];
#pragma unroll
        for (int j = 0; j < NR; ++j) bv[j] = Bs[tap][kk][tx * NR + j];
#pragma unroll
        for (int i = 0; i < 8; ++i)
#pragma unroll
          for (int j = 0; j < NR; ++j)
            acc[i][j] = fmaf(aw[i + tap], bv[j], acc[i][j]);
      }
    }
  }
#pragma unroll
  for (int i = 0; i < 8; ++i) {
    int r = m0 + ty * 8 + i;
#pragma unroll
    for (int j = 0; j < NR; ++j) {
      int c = n0 + tx * NR + j;
      float v = acc[i][j] + bias[c];
      if (ACT == 1) v = fmaxf(v, 0.f);
      if (ACT == 2) v = (v >= 0.f) ? v : 0.01f * v;
      y[(size_t)r * COUT + c] = v;
    }
  }
}

// ---------------- stats + logits + fused finalize (soft/rev/p) --------------
__global__ __launch_bounds__(256) void k_stats3(
    const float* __restrict__ te, const float* __restrict__ me,
    const float* __restrict__ na, const float* __restrict__ nb,
    const int* __restrict__ src_len, const int* __restrict__ mel_len,
    float* __restrict__ val, float* __restrict__ soft, float* __restrict__ rev) {
  const int b = blockIdx.x >> 5;
  const int t0 = (blockIdx.x & 31) << 6;
  const int sl = src_len[b], ml = mel_len[b];
  const int tid = threadIdx.x;
  const int lane = tid & 63, w = tid >> 6;

  if (t0 >= ml) {  // block-uniform: whole t-tile masked
    for (int c = 0; c < 8; ++c) {
      const int s0 = c << 6;
#pragma unroll 4
      for (int i = 0; i < 16; ++i) {
        const int s = s0 + (w << 4) + i;
        size_t o = ((size_t)b * NS_ + s) * NT_ + t0 + lane;
        soft[o] = 0.f;
        rev[o] = 1.f;
      }
    }
    return;
  }

  __shared__ float Bt[DMEL][68];
  __shared__ float At[DMEL][68];
  __shared__ float redm[16][64];
  __shared__ float redz[16][64];
  __shared__ float sm[64];
  __shared__ float srz[64];
  __shared__ float pl[64][65];
  for (int f = tid; f < 64 * 20; f += 256) {
    int row = f / 20, ko = (f % 20) << 2;
    float4 v = *reinterpret_cast<const float4*>(
        &me[((size_t)b * NT_ + t0 + row) * DMEL + ko]);
    Bt[ko][row] = v.x; Bt[ko + 1][row] = v.y; Bt[ko + 2][row] = v.z; Bt[ko + 3][row] = v.w;
  }
  const int sy = tid & 15, tx = tid >> 4;
  const float NEGINF = -__builtin_inff();
  float nbv[4], mACC[4], zACC[4];
#pragma unroll
  for (int j = 0; j < 4; ++j) {
    nbv[j] = nb[b * NT_ + t0 + (tx << 2) + j];
    mACC[j] = NEGINF;
    zACC[j] = 0.f;
  }
  for (int c = 0; c < 8; ++c) {
    const int s0 = c << 6;
    __syncthreads();
    for (int f = tid; f < 64 * 20; f += 256) {
      int row = f / 20, ko = (f % 20) << 2;
      float4 v = *reinterpret_cast<const float4*>(
          &te[((size_t)b * NS_ + s0 + row) * DMEL + ko]);
      At[ko][row] = v.x; At[ko + 1][row] = v.y; At[ko + 2][row] = v.z; At[ko + 3][row] = v.w;
    }
    __syncthreads();
    float acc[4][4];
#pragma unroll
    for (int i = 0; i < 4; ++i)
#pragma unroll
      for (int j = 0; j < 4; ++j) acc[i][j] = 0.f;
#pragma unroll 8
    for (int kk = 0; kk < DMEL; ++kk) {
      float4 a = *reinterpret_cast<const float4*>(&At[kk][sy << 2]);
      float4 bb = *reinterpret_cast<const float4*>(&Bt[kk][tx << 2]);
      float av[4] = {a.x, a.y, a.z, a.w}, bv[4] = {bb.x, bb.y, bb.z, bb.w};
#pragma unroll
      for (int i = 0; i < 4; ++i)
#pragma unroll
        for (int j = 0; j < 4; ++j) acc[i][j] = fmaf(av[i], bv[j], acc[i][j]);
    }
    float nav[4];
#pragma unroll
    for (int i = 0; i < 4; ++i) nav[i] = na[b * NS_ + s0 + (sy << 2) + i];
#pragma unroll
    for (int j = 0; j < 4; ++j) {
      const int t = t0 + (tx << 2) + j;
      const bool tvalid = t < ml;
      float ov[4];
      float mNew = mACC[j];
#pragma unroll
      for (int i = 0; i < 4; ++i) {
        float d2 = (nav[i] + nbv[j]) - 2.0f * acc[i][j];
        float dist = sqrtf(fmaxf(d2, 1e-12f));
        bool valid = ((s0 + (sy << 2) + i) < sl) && tvalid;
        ov[i] = valid ? -dist : -1e9f;
        mNew = fmaxf(mNew, ov[i]);
      }
      float scale = expf(mACC[j] - mNew);
      float zadd = 0.f;
#pragma unroll
      for (int i = 0; i < 4; ++i) zadd += expf(ov[i] - mNew);
      zACC[j] = zACC[j] * scale + zadd;
      mACC[j] = mNew;
      float4 o = make_float4(ov[0], ov[1], ov[2], ov[3]);
      *reinterpret_cast<float4*>(&val[((size_t)b * NT_ + t) * NS_ + s0 + (sy << 2)]) = o;
    }
  }
#pragma unroll
  for (int j = 0; j < 4; ++j) {
    redm[sy][(tx << 2) + j] = mACC[j];
    redz[sy][(tx << 2) + j] = zACC[j];
  }
  __syncthreads();
  if (tid < 64) {
    float M = NEGINF, Z = 0.f;
#pragma unroll
    for (int y = 0; y < 16; ++y) {
      float m = redm[y][tid], z = redz[y][tid];
      float Mn = fmaxf(M, m);
      Z = Z * expf(M - Mn) + z * expf(m - Mn);
      M = Mn;
    }
    sm[tid] = M;
    srz[tid] = 1.0f / Z;
  }
  __syncthreads();

  // pass 2: normalize + transposed soft/rev writes
  for (int c = 0; c < 8; ++c) {
    const int s0 = c << 6;
#pragma unroll
    for (int j = 0; j < 4; ++j) {
      const int tl = (tx << 2) + j;
      const int t = t0 + tl;
      const bool tvalid = t < ml;
      const float mv = sm[tl];
      const float rzv = srz[tl];
      float* vp = &val[((size_t)b * NT_ + t) * NS_ + s0 + (sy << 2)];
      float4 ov = *reinterpret_cast<const float4*>(vp);
      float4 p;
      p.x = tvalid ? expf(ov.x - mv) * rzv : 0.f;
      p.y = tvalid ? expf(ov.y - mv) * rzv : 0.f;
      p.z = tvalid ? expf(ov.z - mv) * rzv : 0.f;
      p.w = tvalid ? expf(ov.w - mv) * rzv : 0.f;
      *reinterpret_cast<float4*>(vp) = p;
      pl[tl][(sy << 2) + 0] = p.x;
      pl[tl][(sy << 2) + 1] = p.y;
      pl[tl][(sy << 2) + 2] = p.z;
      pl[tl][(sy << 2) + 3] = p.w;
    }
    __syncthreads();
#pragma unroll 4
    for (int i = 0; i < 16; ++i) {
      const int s_loc = (w << 4) + i;
      const int s = s0 + s_loc;
      float p = pl[lane][s_loc];
      size_t o = ((size_t)b * NS_ + s) * NT_ + t0 + lane;
      soft[o] = p;
      bool r = (s >= sl) || ((t0 + lane) >= ml);
      rev[o] = r ? 1.0f : 0.0f;
    }
    __syncthreads();
  }
}

// lane i <- lane i-1 via DPP wave_shr:1 (VALU, no LDS pipe). Lane 0 -> 0.
__device__ __forceinline__ float dp_shr1(float x) {
  int r = __builtin_amdgcn_update_dpp(0, __float_as_int(x), 0x138, 0xF, 0xF, true);
  return __int_as_float(r);
}

// RAW barrier: lgkmcnt(0) for cross-wave ds_write visibility, no vmcnt drain.
__device__ __forceinline__ void dp_bar() {
  asm volatile("s_waitcnt lgkmcnt(0)" ::: "memory");
  __builtin_amdgcn_sched_barrier(0);
  __builtin_amdgcn_s_barrier();
}

// Consumer chunk body: 16 rows, 4-row register batches. MASKED = apply (s<=t).
// BUF(d,r,i): row-major view of the LDS union.
#define BUF(d, r, i) lbuf[(((d) << 4) + (r)) * 512 + (i)]
#define DP_CHUNK(MASKED)                                                      \
  _Pragma("unroll")                                                           \
  for (int rb8 = 0; rb8 < 4; ++rb8) {                                         \
    float4 d0[4], d1[4];                                                      \
    _Pragma("unroll")                                                         \
    for (int rr = 0; rr < 4; ++rr) {                                          \
      const float* rp = rowbase + (((rb8 << 2) + rr) << 9);                   \
      d0[rr] = *reinterpret_cast<const float4*>(rp + (lane << 2));            \
      d1[rr] = *reinterpret_cast<const float4*>(rp + 256 + (lane << 2));      \
    }                                                                         \
    _Pragma("unroll")                                                         \
    for (int rr = 0; rr < 4; ++rr) {                                          \
      const int t = tbase + (rb8 << 2) + rr;                                  \
      float cc[8] = {d0[rr].x, d0[rr].y, d0[rr].z, d0[rr].w,                  \
                     d1[rr].x, d1[rr].y, d1[rr].z, d1[rr].w};                 \
      const int sh = t & 31;                                                  \
      if (t < ml) {                                                           \
        float up = dp_shr1(v[7]);                                             \
        float prev = (lane == 0) ? NEGINF : up;                               \
        _Pragma("unroll")                                                     \
        for (int j = 0; j < 8; ++j) {                                         \
          float cur = v[j];                                                   \
          bool keep = cur >= prev;                                            \
          float vm = fmaxf(cur, prev);                                        \
          float vn;                                                           \
          if (MASKED) {                                                       \
            int s = (lane << 3) + j;                                          \
            vn = (s <= t) ? vm + cc[j] : NEGINF;                              \
          } else {                                                            \
            vn = vm + cc[j];                                                  \
          }                                                                   \
          uint32_t bit = keep ? 1u : inv[j];                                  \
          bw[j] |= bit << sh;                                                 \
          v[j] = vn;                                                          \
          prev = cur;                                                         \
        }                                                                     \
      } else {                                                                \
        _Pragma("unroll")                                                     \
        for (int j = 0; j < 8; ++j) bw[j] |= 1u << sh;                        \
      }                                                                       \
    }                                                                         \
  }

// ---------------- DP forward scan + fused backtrack --------------------------
// Scan phase: 1 consumer + 2 reg-staging producer waves, 16-row chunks,
// 64 KB of the LDS union as double buffer. dir words written only for
// t < C_act*16 (walk starts at ml-1; masked region provably keeps idx fixed).
// Backtrack phase (same block): dir is L2-hot -> stage into the 128 KB LDS
// union (buffer lifetime over), tid0 walks, scatters 1.0 into hard.
__global__ __launch_bounds__(192) void k_dp(const float* __restrict__ val,
                                            const int* __restrict__ src_len,
                                            const int* __restrict__ mel_len,
                                            uint32_t* __restrict__ dir,
                                            float* __restrict__ hard) {
  __shared__ uint32_t smem[NS_ * 64];  // 128 KB union: [scan dbuf | bit plane]
  float* lbuf = reinterpret_cast<float*>(smem);
  const int b = blockIdx.x;
  const int wv = threadIdx.x >> 6;   // 0 = consumer, 1..2 = producers
  const int lane = threadIdx.x & 63;
  const float* base = val + (size_t)b * NT_ * NS_;
  const int sl = src_len[b];
  const int ml = mel_len[b];
  const float NEGINF = -__builtin_inff();
  int ca = ((ml + 31) >> 5) << 1;
  const int C_act = ca > 128 ? 128 : ca;

  float4 ra[8], rb[8];
  const int r0 = (wv - 1) << 3;

  float v[8];
  uint32_t bw[8], inv[8];
#pragma unroll
  for (int j = 0; j < 8; ++j) {
    v[j] = 0.0f;
    bw[j] = 0u;
    int s = (lane << 3) + j;
    inv[j] = (s < sl) ? 0u : 1u;
  }

  if (wv > 0) {
#pragma unroll
    for (int rr = 0; rr < 8; ++rr) {
      const float* g = base + (size_t)(r0 + rr) * NS_;
      ra[rr] = *reinterpret_cast<const float4*>(g + (lane << 3));
      rb[rr] = *reinterpret_cast<const float4*>(g + (lane << 3) + 4);
    }
#pragma unroll
    for (int rr = 0; rr < 8; ++rr) {
      float* l = &BUF(0, r0 + rr, 0);
      *reinterpret_cast<float4*>(l + (lane << 2)) = ra[rr];
      *reinterpret_cast<float4*>(l + 256 + (lane << 2)) = rb[rr];
    }
#pragma unroll
    for (int rr = 0; rr < 8; ++rr) {
      const float* g = base + (size_t)(16 + r0 + rr) * NS_;
      ra[rr] = *reinterpret_cast<const float4*>(g + (lane << 3));
      rb[rr] = *reinterpret_cast<const float4*>(g + (lane << 3) + 4);
    }
  }
  dp_bar();

  for (int c = 0; c < C_act; ++c) {
    if (wv > 0) {
      if (c + 1 < C_act) {
        const int nb = (c + 1) & 1;
#pragma unroll
        for (int rr = 0; rr < 8; ++rr) {
          float* l = &BUF(nb, r0 + rr, 0);
          *reinterpret_cast<float4*>(l + (lane << 2)) = ra[rr];
          *reinterpret_cast<float4*>(l + 256 + (lane << 2)) = rb[rr];
        }
      }
      if (c + 2 < C_act) {
        const float* cb = base + ((size_t)(c + 2) * 16 + r0) * NS_;
#pragma unroll
        for (int rr = 0; rr < 8; ++rr) {
          const float* g = cb + (size_t)rr * NS_;
          ra[rr] = *reinterpret_cast<const float4*>(g + (lane << 3));
          rb[rr] = *reinterpret_cast<const float4*>(g + (lane << 3) + 4);
        }
      }
    } else {
      const float* rowbase = &BUF(c & 1, 0, 0);
      const int tbase = c << 4;
      if (c < 32) {
        DP_CHUNK(true)
      } else {
        DP_CHUNK(false)
      }
      if (c & 1) {
        const int c32 = c >> 1;
#pragma unroll
        for (int j = 0; j < 8; ++j) {
          dir[((size_t)(b * NS_) + (lane << 3) + j) * 64 + c32] = bw[j];
          bw[j] = 0u;
        }
      }
    }
    dp_bar();
  }

  // ---- fused backtrack: dir (L2-hot) -> LDS plane; tid0 walks; scatter hard.
  __syncthreads();  // full drain: consumer's dir stores visible block-wide
  const int tid = threadIdx.x;
  const uint32_t* db = dir + (size_t)b * NS_ * 64;
  const int wlim = C_act >> 1;  // valid words per s: wi in [0, wlim)
  for (int f = tid; f < NS_ * wlim; f += 192) {
    int s = f / wlim;
    int wi = f - s * wlim;
    smem[s * 64 + wi] = db[s * 64 + wi];
  }
  __syncthreads();
  if (tid == 0) {
    int idx = sl - 1;
    if (idx < 0) idx = 0;
    if (idx > NS_ - 1) idx = NS_ - 1;
    int cw = -1, ci = -1;
    uint32_t w = 0;
    for (int t = ml - 1; t >= 0; --t) {  // t >= ml: direction=1, idx unchanged
      int wi = t >> 5;
      if (wi != cw || idx != ci) {
        w = smem[idx * 64 + wi];
        cw = wi;
        ci = idx;
      }
      hard[((size_t)(b * NS_) + idx) * NT_ + t] = 1.0f;
      int step = (int)((w >> (t & 31)) & 1) - 1;
      idx += step;
      if (idx < 0) idx = 0;
    }
  }
}

// ---------------- host launch ----------------
extern "C" void kernel_launch(void* const* d_in, const int* in_sizes, int n_in,
                              void* d_out, int out_size, void* d_ws, size_t ws_size,
                              hipStream_t stream) {
  if (n_in != 17) return;
  if (ws_size < FULL_NEED) return;

  const float* text = (const float*)d_in[0];
  const float* mel = (const float*)d_in[1];
  const int* src_len = (const int*)d_in[2];
  const int* mel_len = (const int*)d_in[3];
  const float* tw1 = (const float*)d_in[7];
  const float* tb1 = (const float*)d_in[8];
  const float* tw2 = (const float*)d_in[9];
  const float* tb2 = (const float*)d_in[10];
  const float* mw1 = (const float*)d_in[11];
  const float* mb1 = (const float*)d_in[12];
  const float* mw2 = (const float*)d_in[13];
  const float* mb2 = (const float*)d_in[14];
  const float* mw3 = (const float*)d_in[15];
  const float* mb3 = (const float*)d_in[16];

  char* w8 = (char*)d_ws;
  float* melh1 = (float*)(w8 + 0);            // (B,T,160) 41.9 MB
  float* mh2 = (float*)(w8 + 41943040ull);    // (B,T,80)  21.0 MB
  float* texth1 = (float*)(w8 + 62914560ull); // (B,S,512) 33.5 MB
  float* val = (float*)(w8 + 0);              // (B,T,S) written after convs

  float* te = (float*)(w8 + P + PO_TE);
  float* me = (float*)(w8 + P + PO_ME);
  float* na = (float*)(w8 + P + PO_NA);
  float* nb = (float*)(w8 + P + PO_NB);
  float* wt1 = (float*)(w8 + P + PO_W1);
  float* wt2 = (float*)(w8 + P + PO_W2);
  float* wt3 = (float*)(w8 + P + PO_W3);
  float* wt4 = (float*)(w8 + P + PO_W4);
  float* wt5 = (float*)(w8 + P + PO_W5);
  uint32_t* dir = (uint32_t*)(w8 + P + PO_DIR);

  // outputs are float32
  float* soft = (float*)d_out;
  float* hard = soft + (size_t)NB_ * NS_ * NT_;
  float* rev = soft + 2 * (size_t)NB_ * NS_ * NT_;

  // all weight transposes in one launch
  k_wtrans_all<<<(517376 + 255) / 256, 256, 0, stream>>>(
      tw1, wt1, tw2, wt2, mw1, wt3, mw2, wt4, mw3, wt5);

  // encoders (inputs read directly as f32); norms fused into final convs
  k_conv3<80, 160, 80, 5, 16, 11, 2><<<512 * 2, 256, 0, stream>>>(mel, wt3, mb1, melh1);
  k_conv3<160, 80, 80, 5, 32, 11, 2><<<512 * 1, 256, 0, stream>>>(melh1, wt4, mb2, mh2);
  k_conv<80, 80, 80, 5, 16, 11, 0, true, true><<<512 * 1, 256, 0, stream>>>(mh2, wt5, mb3, me, mel_len, nb);
  k_conv3<256, 512, 128, 8, 32, 9, 1><<<128 * 4, 256, 0, stream>>>(text, wt1, tb1, texth1);
  k_conv<512, 80, 80, 5, 32, 9, 0, true, true><<<128 * 1, 256, 0, stream>>>(texth1, wt2, tb2, te, src_len, na);

  // hard_A zero early (device-wide memset BW); k_dp's fused walk scatters 1s
  hipMemsetAsync(hard, 0, (size_t)NB_ * NS_ * NT_ * 4, stream);

  // stats + logits + fused finalize (val=p, soft, rev)
  k_stats3<<<NB_ * 32, 256, 0, stream>>>(te, me, na, nb, src_len, mel_len, val, soft, rev);

  // DP scan + fused backtrack
  k_dp<<<NB_, 192, 0, stream>>>(val, src_len, mel_len, dir, hard);
}

// Round 22
// 1108.445 us; speedup vs baseline: 1.3593x; 1.0052x over previous
//
#include <hip/hip_runtime.h>
#include <hip/hip_bf16.h>
#include <cstdint>

// Problem constants
constexpr int NB_ = 32;     // batch
constexpr int NS_ = 512;    // text length S
constexpr int NT_ = 2048;   // mel length T
constexpr int DMEL = 80;    // embedding dim

// ---------------- workspace layout ----------------
constexpr size_t P = 134217728ull;  // persistent block base
constexpr size_t PO_TE   = 0ull;
constexpr size_t PO_ME   = 5242880ull;
constexpr size_t PO_NA   = 26214400ull;
constexpr size_t PO_NB   = 26279936ull;
constexpr size_t PO_W1   = 27066368ull;
constexpr size_t PO_W2   = 28639232ull;
constexpr size_t PO_W3   = 28803072ull;
constexpr size_t PO_W4   = 28956672ull;
constexpr size_t PO_W5   = 29110272ull;
constexpr size_t PO_DIR  = 29139968ull;
constexpr size_t FULL_NEED = P + 33334528ull;

// ---------------- fused weight transposes (all 5 weights, one launch) -------
__global__ void k_wtrans_all(const float* __restrict__ w1, float* __restrict__ o1,
                             const float* __restrict__ w2, float* __restrict__ o2,
                             const float* __restrict__ w3, float* __restrict__ o3,
                             const float* __restrict__ w4, float* __restrict__ o4,
                             const float* __restrict__ w5, float* __restrict__ o5) {
  int id = blockIdx.x * 256 + threadIdx.x;
  const float* w;
  float* o;
  int CO, CI, KW;
  if (id < 393216) {
    w = w1; o = o1; CO = 512; CI = 256; KW = 3;
  } else if (id < 434176) {
    id -= 393216; w = w2; o = o2; CO = 80; CI = 512; KW = 1;
  } else if (id < 472576) {
    id -= 434176; w = w3; o = o3; CO = 160; CI = 80; KW = 3;
  } else if (id < 510976) {
    id -= 472576; w = w4; o = o4; CO = 80; CI = 160; KW = 3;
  } else if (id < 517376) {
    id -= 510976; w = w5; o = o5; CO = 80; CI = 80; KW = 1;
  } else {
    return;
  }
  int co = id % CO;
  int rest = id / CO;
  int ci = rest % CI;
  int tap = rest / CI;
  o[id] = w[(co * CI + ci) * KW + tap];
}

// ---------------- conv1d K=1 as implicit GEMM, optional fused row-norm ------
template <int CIN, int COUT, int NTILE, int NR, int KC, int LOG2L, int ACT,
          bool MASK, bool NORM>
__global__ __launch_bounds__(256) void k_conv(const float* __restrict__ x,
                                              const float* __restrict__ wT,
                                              const float* __restrict__ bias,
                                              float* __restrict__ y,
                                              const int* __restrict__ lenArr,
                                              float* __restrict__ normout) {
  constexpr int L = 1 << LOG2L;
  constexpr int MT = 128;
  constexpr int APAD = 132;
  constexpr int BPAD = NTILE + 4;
  __shared__ float As[KC][APAD];
  __shared__ float Bs[KC][BPAD];

  const int tid = threadIdx.x;
  const int tx = tid & 15;
  const int ty = tid >> 4;
  constexpr int NBLK = COUT / NTILE;
  const int m0 = (blockIdx.x / NBLK) * MT;
  const int n0 = (blockIdx.x % NBLK) * NTILE;

  float acc[8][NR];
#pragma unroll
  for (int i = 0; i < 8; ++i)
#pragma unroll
    for (int j = 0; j < NR; ++j) acc[i][j] = 0.f;

  for (int k0 = 0; k0 < CIN; k0 += KC) {
    __syncthreads();
    constexpr int AF4 = MT * KC / 4;
    constexpr int F4R = KC / 4;
    for (int f = tid; f < AF4; f += 256) {
      int row = f / F4R;
      int ko = (f % F4R) * 4;
      int r = m0 + row;
      float4 v = *reinterpret_cast<const float4*>(&x[(size_t)r * CIN + k0 + ko]);
      As[ko + 0][row] = v.x;
      As[ko + 1][row] = v.y;
      As[ko + 2][row] = v.z;
      As[ko + 3][row] = v.w;
    }
    constexpr int BF4 = KC * NTILE / 4;
    constexpr int BF4R = NTILE / 4;
    for (int f = tid; f < BF4; f += 256) {
      int kk = f / BF4R;
      int no = (f % BF4R) * 4;
      float4 v = *reinterpret_cast<const float4*>(
          &wT[((size_t)(k0 + kk)) * COUT + n0 + no]);
      *reinterpret_cast<float4*>(&Bs[kk][no]) = v;
    }
    __syncthreads();
#pragma unroll 8
    for (int kk = 0; kk < KC; ++kk) {
      float4 a0 = *reinterpret_cast<const float4*>(&As[kk][ty * 8]);
      float4 a1 = *reinterpret_cast<const float4*>(&As[kk][ty * 8 + 4]);
      float av[8] = {a0.x, a0.y, a0.z, a0.w, a1.x, a1.y, a1.z, a1.w};
      float bv[NR];
#pragma unroll
      for (int j = 0; j < NR; ++j) bv[j] = Bs[kk][tx * NR + j];
#pragma unroll
      for (int i = 0; i < 8; ++i)
#pragma unroll
        for (int j = 0; j < NR; ++j) acc[i][j] = fmaf(av[i], bv[j], acc[i][j]);
    }
  }
#pragma unroll
  for (int i = 0; i < 8; ++i) {
    int r = m0 + ty * 8 + i;
    int b = r >> LOG2L;
    int pos = r & (L - 1);
    bool zero = MASK && (pos >= lenArr[b]);
    float sq = 0.f;
#pragma unroll
    for (int j = 0; j < NR; ++j) {
      int c = n0 + tx * NR + j;
      float v = acc[i][j] + bias[c];
      if (ACT == 1) v = fmaxf(v, 0.f);
      if (ACT == 2) v = (v >= 0.f) ? v : 0.01f * v;
      if (zero) v = 0.f;
      y[(size_t)r * COUT + c] = v;
      if (NORM) sq = fmaf(v, v, sq);
    }
    if (NORM) {
      sq += __shfl_xor(sq, 1);
      sq += __shfl_xor(sq, 2);
      sq += __shfl_xor(sq, 4);
      sq += __shfl_xor(sq, 8);
      if (tx == 0) normout[r] = sq;
    }
  }
}

// ---------------- conv1d K=3: halo-staged A (once per k0), all taps inner ----
template <int CIN, int COUT, int NTILE, int NR, int KC, int LOG2L, int ACT>
__global__ __launch_bounds__(256) void k_conv3(const float* __restrict__ x,
                                               const float* __restrict__ wT,
                                               const float* __restrict__ bias,
                                               float* __restrict__ y) {
  constexpr int L = 1 << LOG2L;
  constexpr int MT = 128;
  constexpr int MT2 = MT + 2;
  constexpr int APAD = 132;
  constexpr int BPAD = NTILE + 4;
  __shared__ float As[KC][APAD];
  __shared__ float Bs[3][KC][BPAD];

  const int tid = threadIdx.x;
  const int tx = tid & 15;
  const int ty = tid >> 4;
  constexpr int NBLK = COUT / NTILE;
  const int m0 = (blockIdx.x / NBLK) * MT;
  const int n0 = (blockIdx.x % NBLK) * NTILE;
  const bool zlo = (m0 & (L - 1)) == 0;
  const bool zhi = ((m0 + MT) & (L - 1)) == 0;
  constexpr int TOTR = NB_ << LOG2L;

  float acc[8][NR];
#pragma unroll
  for (int i = 0; i < 8; ++i)
#pragma unroll
    for (int j = 0; j < NR; ++j) acc[i][j] = 0.f;

  for (int k0 = 0; k0 < CIN; k0 += KC) {
    __syncthreads();
    constexpr int F4R = KC / 4;
    for (int f = tid; f < MT2 * F4R; f += 256) {
      int h = f / F4R;
      int ko = (f % F4R) * 4;
      int g = m0 + h - 1;
      bool zero = (h == 0 && zlo) || (h == MT + 1 && zhi);
      int gc = g < 0 ? 0 : (g >= TOTR ? TOTR - 1 : g);
      float4 v = *reinterpret_cast<const float4*>(&x[(size_t)gc * CIN + k0 + ko]);
      if (zero) v = make_float4(0.f, 0.f, 0.f, 0.f);
      As[ko + 0][h] = v.x;
      As[ko + 1][h] = v.y;
      As[ko + 2][h] = v.z;
      As[ko + 3][h] = v.w;
    }
    constexpr int BF4R = NTILE / 4;
    for (int f = tid; f < 3 * KC * BF4R; f += 256) {
      int tap = f / (KC * BF4R);
      int rem = f % (KC * BF4R);
      int kk = rem / BF4R;
      int no = (rem % BF4R) * 4;
      float4 v = *reinterpret_cast<const float4*>(
          &wT[((size_t)(tap * CIN + k0 + kk)) * COUT + n0 + no]);
      *reinterpret_cast<float4*>(&Bs[tap][kk][no]) = v;
    }
    __syncthreads();
#pragma unroll 4
    for (int kk = 0; kk < KC; ++kk) {
      float aw[10];
      float4 a0 = *reinterpret_cast<const float4*>(&As[kk][ty * 8]);
      float4 a1 = *reinterpret_cast<const float4*>(&As[kk][ty * 8 + 4]);
      float2 a2 = *reinterpret_cast<const float2*>(&As[kk][ty * 8 + 8]);
      aw[0] = a0.x; aw[1] = a0.y; aw[2] = a0.z; aw[3] = a0.w;
      aw[4] = a1.x; aw[5] = a1.y; aw[6] = a1.z; aw[7] = a1.w;
      aw[8] = a2.x; aw[9] = a2.y;
#pragma unroll
      for (int tap = 0; tap < 3; ++tap) {
        float bv[NR];
#pragma unroll
        for (int j = 0; j < NR; ++j) bv[j] = Bs[tap][kk][tx * NR + j];
#pragma unroll
        for (int i = 0; i < 8; ++i)
#pragma unroll
          for (int j = 0; j < NR; ++j)
            acc[i][j] = fmaf(aw[i + tap], bv[j], acc[i][j]);
      }
    }
  }
#pragma unroll
  for (int i = 0; i < 8; ++i) {
    int r = m0 + ty * 8 + i;
#pragma unroll
    for (int j = 0; j < NR; ++j) {
      int c = n0 + tx * NR + j;
      float v = acc[i][j] + bias[c];
      if (ACT == 1) v = fmaxf(v, 0.f);
      if (ACT == 2) v = (v >= 0.f) ? v : 0.01f * v;
      y[(size_t)r * COUT + c] = v;
    }
  }
}

// ---------------- stats + logits + fused finalize (soft/rev/p) --------------
__global__ __launch_bounds__(256) void k_stats3(
    const float* __restrict__ te, const float* __restrict__ me,
    const float* __restrict__ na, const float* __restrict__ nb,
    const int* __restrict__ src_len, const int* __restrict__ mel_len,
    float* __restrict__ val, float* __restrict__ soft, float* __restrict__ rev) {
  const int b = blockIdx.x >> 5;
  const int t0 = (blockIdx.x & 31) << 6;
  const int sl = src_len[b], ml = mel_len[b];
  const int tid = threadIdx.x;
  const int lane = tid & 63, w = tid >> 6;

  if (t0 >= ml) {  // block-uniform: whole t-tile masked
    for (int c = 0; c < 8; ++c) {
      const int s0 = c << 6;
#pragma unroll 4
      for (int i = 0; i < 16; ++i) {
        const int s = s0 + (w << 4) + i;
        size_t o = ((size_t)b * NS_ + s) * NT_ + t0 + lane;
        soft[o] = 0.f;
        rev[o] = 1.f;
      }
    }
    return;
  }

  __shared__ float Bt[DMEL][68];
  __shared__ float At[DMEL][68];
  __shared__ float redm[16][64];
  __shared__ float redz[16][64];
  __shared__ float sm[64];
  __shared__ float srz[64];
  __shared__ float pl[64][65];
  for (int f = tid; f < 64 * 20; f += 256) {
    int row = f / 20, ko = (f % 20) << 2;
    float4 v = *reinterpret_cast<const float4*>(
        &me[((size_t)b * NT_ + t0 + row) * DMEL + ko]);
    Bt[ko][row] = v.x; Bt[ko + 1][row] = v.y; Bt[ko + 2][row] = v.z; Bt[ko + 3][row] = v.w;
  }
  const int sy = tid & 15, tx = tid >> 4;
  const float NEGINF = -__builtin_inff();
  float nbv[4], mACC[4], zACC[4];
#pragma unroll
  for (int j = 0; j < 4; ++j) {
    nbv[j] = nb[b * NT_ + t0 + (tx << 2) + j];
    mACC[j] = NEGINF;
    zACC[j] = 0.f;
  }
  for (int c = 0; c < 8; ++c) {
    const int s0 = c << 6;
    __syncthreads();
    for (int f = tid; f < 64 * 20; f += 256) {
      int row = f / 20, ko = (f % 20) << 2;
      float4 v = *reinterpret_cast<const float4*>(
          &te[((size_t)b * NS_ + s0 + row) * DMEL + ko]);
      At[ko][row] = v.x; At[ko + 1][row] = v.y; At[ko + 2][row] = v.z; At[ko + 3][row] = v.w;
    }
    __syncthreads();
    float acc[4][4];
#pragma unroll
    for (int i = 0; i < 4; ++i)
#pragma unroll
      for (int j = 0; j < 4; ++j) acc[i][j] = 0.f;
#pragma unroll 8
    for (int kk = 0; kk < DMEL; ++kk) {
      float4 a = *reinterpret_cast<const float4*>(&At[kk][sy << 2]);
      float4 bb = *reinterpret_cast<const float4*>(&Bt[kk][tx << 2]);
      float av[4] = {a.x, a.y, a.z, a.w}, bv[4] = {bb.x, bb.y, bb.z, bb.w};
#pragma unroll
      for (int i = 0; i < 4; ++i)
#pragma unroll
        for (int j = 0; j < 4; ++j) acc[i][j] = fmaf(av[i], bv[j], acc[i][j]);
    }
    float nav[4];
#pragma unroll
    for (int i = 0; i < 4; ++i) nav[i] = na[b * NS_ + s0 + (sy << 2) + i];
#pragma unroll
    for (int j = 0; j < 4; ++j) {
      const int t = t0 + (tx << 2) + j;
      const bool tvalid = t < ml;
      float ov[4];
      float mNew = mACC[j];
#pragma unroll
      for (int i = 0; i < 4; ++i) {
        float d2 = (nav[i] + nbv[j]) - 2.0f * acc[i][j];
        float dist = sqrtf(fmaxf(d2, 1e-12f));
        bool valid = ((s0 + (sy << 2) + i) < sl) && tvalid;
        ov[i] = valid ? -dist : -1e9f;
        mNew = fmaxf(mNew, ov[i]);
      }
      float scale = expf(mACC[j] - mNew);
      float zadd = 0.f;
#pragma unroll
      for (int i = 0; i < 4; ++i) zadd += expf(ov[i] - mNew);
      zACC[j] = zACC[j] * scale + zadd;
      mACC[j] = mNew;
      float4 o = make_float4(ov[0], ov[1], ov[2], ov[3]);
      *reinterpret_cast<float4*>(&val[((size_t)b * NT_ + t) * NS_ + s0 + (sy << 2)]) = o;
    }
  }
#pragma unroll
  for (int j = 0; j < 4; ++j) {
    redm[sy][(tx << 2) + j] = mACC[j];
    redz[sy][(tx << 2) + j] = zACC[j];
  }
  __syncthreads();
  if (tid < 64) {
    float M = NEGINF, Z = 0.f;
#pragma unroll
    for (int y = 0; y < 16; ++y) {
      float m = redm[y][tid], z = redz[y][tid];
      float Mn = fmaxf(M, m);
      Z = Z * expf(M - Mn) + z * expf(m - Mn);
      M = Mn;
    }
    sm[tid] = M;
    srz[tid] = 1.0f / Z;
  }
  __syncthreads();

  // pass 2: normalize + transposed soft/rev writes
  for (int c = 0; c < 8; ++c) {
    const int s0 = c << 6;
#pragma unroll
    for (int j = 0; j < 4; ++j) {
      const int tl = (tx << 2) + j;
      const int t = t0 + tl;
      const bool tvalid = t < ml;
      const float mv = sm[tl];
      const float rzv = srz[tl];
      float* vp = &val[((size_t)b * NT_ + t) * NS_ + s0 + (sy << 2)];
      float4 ov = *reinterpret_cast<const float4*>(vp);
      float4 p;
      p.x = tvalid ? expf(ov.x - mv) * rzv : 0.f;
      p.y = tvalid ? expf(ov.y - mv) * rzv : 0.f;
      p.z = tvalid ? expf(ov.z - mv) * rzv : 0.f;
      p.w = tvalid ? expf(ov.w - mv) * rzv : 0.f;
      *reinterpret_cast<float4*>(vp) = p;
      pl[tl][(sy << 2) + 0] = p.x;
      pl[tl][(sy << 2) + 1] = p.y;
      pl[tl][(sy << 2) + 2] = p.z;
      pl[tl][(sy << 2) + 3] = p.w;
    }
    __syncthreads();
#pragma unroll 4
    for (int i = 0; i < 16; ++i) {
      const int s_loc = (w << 4) + i;
      const int s = s0 + s_loc;
      float p = pl[lane][s_loc];
      size_t o = ((size_t)b * NS_ + s) * NT_ + t0 + lane;
      soft[o] = p;
      bool r = (s >= sl) || ((t0 + lane) >= ml);
      rev[o] = r ? 1.0f : 0.0f;
    }
    __syncthreads();
  }
}

// lane i <- lane i-1 via DPP wave_shr:1 (VALU, no LDS pipe). Lane 0 -> 0.
__device__ __forceinline__ float dp_shr1(float x) {
  int r = __builtin_amdgcn_update_dpp(0, __float_as_int(x), 0x138, 0xF, 0xF, true);
  return __int_as_float(r);
}

// RAW barrier: lgkmcnt(0) for cross-wave ds_write visibility, no vmcnt drain.
__device__ __forceinline__ void dp_bar() {
  asm volatile("s_waitcnt lgkmcnt(0)" ::: "memory");
  __builtin_amdgcn_sched_barrier(0);
  __builtin_amdgcn_s_barrier();
}

// Consumer chunk body: 16 rows, 4-row register batches. MASKED = apply (s<=t).
// BUF(d,r,i): row-major view of the float-typed LDS union (16B aligned).
#define BUF(d, r, i) lbuf[(((d) << 4) + (r)) * 512 + (i)]
#define DP_CHUNK(MASKED)                                                      \
  _Pragma("unroll")                                                           \
  for (int rb8 = 0; rb8 < 4; ++rb8) {                                         \
    float4 d0[4], d1[4];                                                      \
    _Pragma("unroll")                                                         \
    for (int rr = 0; rr < 4; ++rr) {                                          \
      const float* rp = rowbase + (((rb8 << 2) + rr) << 9);                   \
      d0[rr] = *reinterpret_cast<const float4*>(rp + (lane << 2));            \
      d1[rr] = *reinterpret_cast<const float4*>(rp + 256 + (lane << 2));      \
    }                                                                         \
    _Pragma("unroll")                                                         \
    for (int rr = 0; rr < 4; ++rr) {                                          \
      const int t = tbase + (rb8 << 2) + rr;                                  \
      float cc[8] = {d0[rr].x, d0[rr].y, d0[rr].z, d0[rr].w,                  \
                     d1[rr].x, d1[rr].y, d1[rr].z, d1[rr].w};                 \
      const int sh = t & 31;                                                  \
      if (t < ml) {                                                           \
        float up = dp_shr1(v[7]);                                             \
        float prev = (lane == 0) ? NEGINF : up;                               \
        _Pragma("unroll")                                                     \
        for (int j = 0; j < 8; ++j) {                                         \
          float cur = v[j];                                                   \
          bool keep = cur >= prev;                                            \
          float vm = fmaxf(cur, prev);                                        \
          float vn;                                                           \
          if (MASKED) {                                                       \
            int s = (lane << 3) + j;                                          \
            vn = (s <= t) ? vm + cc[j] : NEGINF;                              \
          } else {                                                            \
            vn = vm + cc[j];                                                  \
          }                                                                   \
          uint32_t bit = keep ? 1u : inv[j];                                  \
          bw[j] |= bit << sh;                                                 \
          v[j] = vn;                                                          \
          prev = cur;                                                         \
        }                                                                     \
      } else {                                                                \
        _Pragma("unroll")                                                     \
        for (int j = 0; j < 8; ++j) bw[j] |= 1u << sh;                        \
      }                                                                       \
    }                                                                         \
  }

// ---------------- DP forward scan + fused backtrack --------------------------
// Scan: 1 consumer + 2 producer waves, 16-row chunks, first 64 KB of the
// float-typed 128 KB LDS union (native float4 access -> conflict-free b128).
// Backtrack: dir (L2-hot) staged via uint4 16B copies into the full union,
// tid0 walks from t=ml-1 (masked region provably keeps idx fixed), scatters.
__global__ __launch_bounds__(192) void k_dp(const float* __restrict__ val,
                                            const int* __restrict__ src_len,
                                            const int* __restrict__ mel_len,
                                            uint32_t* __restrict__ dir,
                                            float* __restrict__ hard) {
  __shared__ __align__(16) float lbuf[NS_ * 64];  // 128 KB union
  const int b = blockIdx.x;
  const int wv = threadIdx.x >> 6;   // 0 = consumer, 1..2 = producers
  const int lane = threadIdx.x & 63;
  const float* base = val + (size_t)b * NT_ * NS_;
  const int sl = src_len[b];
  const int ml = mel_len[b];
  const float NEGINF = -__builtin_inff();
  int ca = ((ml + 31) >> 5) << 1;
  const int C_act = ca > 128 ? 128 : ca;

  float4 ra[8], rb[8];
  const int r0 = (wv - 1) << 3;

  float v[8];
  uint32_t bw[8], inv[8];
#pragma unroll
  for (int j = 0; j < 8; ++j) {
    v[j] = 0.0f;
    bw[j] = 0u;
    int s = (lane << 3) + j;
    inv[j] = (s < sl) ? 0u : 1u;
  }

  if (wv > 0) {
#pragma unroll
    for (int rr = 0; rr < 8; ++rr) {
      const float* g = base + (size_t)(r0 + rr) * NS_;
      ra[rr] = *reinterpret_cast<const float4*>(g + (lane << 3));
      rb[rr] = *reinterpret_cast<const float4*>(g + (lane << 3) + 4);
    }
#pragma unroll
    for (int rr = 0; rr < 8; ++rr) {
      float* l = &BUF(0, r0 + rr, 0);
      *reinterpret_cast<float4*>(l + (lane << 2)) = ra[rr];
      *reinterpret_cast<float4*>(l + 256 + (lane << 2)) = rb[rr];
    }
#pragma unroll
    for (int rr = 0; rr < 8; ++rr) {
      const float* g = base + (size_t)(16 + r0 + rr) * NS_;
      ra[rr] = *reinterpret_cast<const float4*>(g + (lane << 3));
      rb[rr] = *reinterpret_cast<const float4*>(g + (lane << 3) + 4);
    }
  }
  dp_bar();

  for (int c = 0; c < C_act; ++c) {
    if (wv > 0) {
      if (c + 1 < C_act) {
        const int nb = (c + 1) & 1;
#pragma unroll
        for (int rr = 0; rr < 8; ++rr) {
          float* l = &BUF(nb, r0 + rr, 0);
          *reinterpret_cast<float4*>(l + (lane << 2)) = ra[rr];
          *reinterpret_cast<float4*>(l + 256 + (lane << 2)) = rb[rr];
        }
      }
      if (c + 2 < C_act) {
        const float* cb = base + ((size_t)(c + 2) * 16 + r0) * NS_;
#pragma unroll
        for (int rr = 0; rr < 8; ++rr) {
          const float* g = cb + (size_t)rr * NS_;
          ra[rr] = *reinterpret_cast<const float4*>(g + (lane << 3));
          rb[rr] = *reinterpret_cast<const float4*>(g + (lane << 3) + 4);
        }
      }
    } else {
      const float* rowbase = &BUF(c & 1, 0, 0);
      const int tbase = c << 4;
      if (c < 32) {
        DP_CHUNK(true)
      } else {
        DP_CHUNK(false)
      }
      if (c & 1) {
        const int c32 = c >> 1;
#pragma unroll
        for (int j = 0; j < 8; ++j) {
          dir[((size_t)(b * NS_) + (lane << 3) + j) * 64 + c32] = bw[j];
          bw[j] = 0u;
        }
      }
    }
    dp_bar();
  }

  // ---- fused backtrack: dir (L2-hot) -> LDS plane (uint4 copies); walk.
  __syncthreads();  // full drain: consumer's dir stores visible block-wide
  uint32_t* uplane = reinterpret_cast<uint32_t*>(lbuf);
  const int tid = threadIdx.x;
  const uint32_t* db = dir + (size_t)b * NS_ * 64;
  for (int f = tid; f < 8192; f += 192) {  // all 64 words/row; walk reads < wlim only
    int s = f >> 4;
    int wo = (f & 15) << 2;
    *reinterpret_cast<uint4*>(&uplane[s * 64 + wo]) =
        *reinterpret_cast<const uint4*>(&db[s * 64 + wo]);
  }
  __syncthreads();
  if (tid == 0) {
    int idx = sl - 1;
    if (idx < 0) idx = 0;
    if (idx > NS_ - 1) idx = NS_ - 1;
    int cw = -1, ci = -1;
    uint32_t w = 0;
    for (int t = ml - 1; t >= 0; --t) {  // t >= ml: direction=1, idx unchanged
      int wi = t >> 5;
      if (wi != cw || idx != ci) {
        w = uplane[idx * 64 + wi];
        cw = wi;
        ci = idx;
      }
      hard[((size_t)(b * NS_) + idx) * NT_ + t] = 1.0f;
      int step = (int)((w >> (t & 31)) & 1) - 1;
      idx += step;
      if (idx < 0) idx = 0;
    }
  }
}

// ---------------- host launch ----------------
extern "C" void kernel_launch(void* const* d_in, const int* in_sizes, int n_in,
                              void* d_out, int out_size, void* d_ws, size_t ws_size,
                              hipStream_t stream) {
  if (n_in != 17) return;
  if (ws_size < FULL_NEED) return;

  const float* text = (const float*)d_in[0];
  const float* mel = (const float*)d_in[1];
  const int* src_len = (const int*)d_in[2];
  const int* mel_len = (const int*)d_in[3];
  const float* tw1 = (const float*)d_in[7];
  const float* tb1 = (const float*)d_in[8];
  const float* tw2 = (const float*)d_in[9];
  const float* tb2 = (const float*)d_in[10];
  const float* mw1 = (const float*)d_in[11];
  const float* mb1 = (const float*)d_in[12];
  const float* mw2 = (const float*)d_in[13];
  const float* mb2 = (const float*)d_in[14];
  const float* mw3 = (const float*)d_in[15];
  const float* mb3 = (const float*)d_in[16];

  char* w8 = (char*)d_ws;
  float* melh1 = (float*)(w8 + 0);            // (B,T,160) 41.9 MB
  float* mh2 = (float*)(w8 + 41943040ull);    // (B,T,80)  21.0 MB
  float* texth1 = (float*)(w8 + 62914560ull); // (B,S,512) 33.5 MB
  float* val = (float*)(w8 + 0);              // (B,T,S) written after convs

  float* te = (float*)(w8 + P + PO_TE);
  float* me = (float*)(w8 + P + PO_ME);
  float* na = (float*)(w8 + P + PO_NA);
  float* nb = (float*)(w8 + P + PO_NB);
  float* wt1 = (float*)(w8 + P + PO_W1);
  float* wt2 = (float*)(w8 + P + PO_W2);
  float* wt3 = (float*)(w8 + P + PO_W3);
  float* wt4 = (float*)(w8 + P + PO_W4);
  float* wt5 = (float*)(w8 + P + PO_W5);
  uint32_t* dir = (uint32_t*)(w8 + P + PO_DIR);

  // outputs are float32
  float* soft = (float*)d_out;
  float* hard = soft + (size_t)NB_ * NS_ * NT_;
  float* rev = soft + 2 * (size_t)NB_ * NS_ * NT_;

  // all weight transposes in one launch
  k_wtrans_all<<<(517376 + 255) / 256, 256, 0, stream>>>(
      tw1, wt1, tw2, wt2, mw1, wt3, mw2, wt4, mw3, wt5);

  // encoders (inputs read directly as f32); norms fused into final convs
  k_conv3<80, 160, 80, 5, 16, 11, 2><<<512 * 2, 256, 0, stream>>>(mel, wt3, mb1, melh1);
  k_conv3<160, 80, 80, 5, 32, 11, 2><<<512 * 1, 256, 0, stream>>>(melh1, wt4, mb2, mh2);
  k_conv<80, 80, 80, 5, 16, 11, 0, true, true><<<512 * 1, 256, 0, stream>>>(mh2, wt5, mb3, me, mel_len, nb);
  k_conv3<256, 512, 128, 8, 32, 9, 1><<<128 * 4, 256, 0, stream>>>(text, wt1, tb1, texth1);
  k_conv<512, 80, 80, 5, 32, 9, 0, true, true><<<128 * 1, 256, 0, stream>>>(texth1, wt2, tb2, te, src_len, na);

  // hard_A zero early (device-wide memset BW); k_dp's fused walk scatters 1s
  hipMemsetAsync(hard, 0, (size_t)NB_ * NS_ * NT_ * 4, stream);

  // stats + logits + fused finalize (val=p, soft, rev)
  k_stats3<<<NB_ * 32, 256, 0, stream>>>(te, me, na, nb, src_len, mel_len, val, soft, rev);

  // DP scan + fused backtrack
  k_dp<<<NB_, 192, 0, stream>>>(val, src_len, mel_len, dir, hard);
}